// Round 2
// baseline (207.588 us; speedup 1.0000x reference)
//
#include <hip/hip_runtime.h>
#include <math.h>

// Problem constants: B=4, L=T=2048, H=8, E=64, C=H*E=512, top_k=7
// Output = cumsum(V) with top-7 rows (by corrmean) replaced by running mean.
// Only the top-7 index SET of corrmean affects the output -> grams in bf16
// MFMA. Temporal LSE uses fixed exp-offset 80; sum-only partials.
// R6: symmetric gram -> upper-triangle tiles only.
// R9: cumsum split into full-GPU psum+write phases (neutral: inputs are
//     L3-resident, old version was already ~10 us — model updated).
// R10 (this round): temporal gram was the measured bottleneck (59 us,
//     MfmaUtil 23% = the 2-phase drain-barrier ceiling). Rewritten as
//     256x256 tile, 512 thr / 8 waves (2Mx4N), BK=32, 4-deep LDS ring
//     (128 KB dynamic), counted s_waitcnt vmcnt(12) (never 0 in-loop),
//     raw s_barrier, setprio around MFMA cluster. Chunk-XOR LDS swizzle
//     and fragment addressing reused verbatim from the verified R7 kernel
//     (bank-conflict 0). Epilogue: row slots cj*4+wc, col slots ri*2+wr;
//     gap slots [2R,4R) zeroed by convert_bf16 (1 float/thread).

typedef __attribute__((ext_vector_type(8))) short short8;
typedef __attribute__((ext_vector_type(8))) unsigned short ushort8;
typedef __attribute__((ext_vector_type(4))) float f32x4;

typedef const __attribute__((address_space(1))) void* gas_ptr;
typedef __attribute__((address_space(3))) void* las_ptr;

#define EXP_OFF 80.0f

__device__ __forceinline__ void async_cp16(const void* g, void* l) {
  // LDS dest is wave-uniform base; HW adds lane*16 (m104/m108).
  __builtin_amdgcn_global_load_lds((gas_ptr)g, (las_ptr)l, 16, 0, 0);
}

__device__ __forceinline__ unsigned short f2bf(float x) {
  union { float f; unsigned int u; } v; v.f = x;
  unsigned int r = v.u + 0x7FFFu + ((v.u >> 16) & 1u);  // RNE
  return (unsigned short)(r >> 16);
}

// ---------------------------------------------------------------------------
// Convert Q,K fp32 -> Z bf16 [4][4096][512] (rows 0..2047 = Q, 2048.. = K).
// Also zero-fills part[1048576] (one float per thread) so the temporal
// epilogue's unused slots read as 0 in merge_row.
// ---------------------------------------------------------------------------
__global__ __launch_bounds__(256) void convert_bf16_kernel(
    const float* __restrict__ Q, const float* __restrict__ K,
    unsigned short* __restrict__ Z, float* __restrict__ part) {
  int tid = blockIdx.x * 256 + threadIdx.x;  // 0..1048575
  part[tid] = 0.f;                           // part = 4*4096*64 floats exactly
  int row = tid >> 6;                        // b*4096 + i
  int c0 = (tid & 63) * 8;
  int b = row >> 12, i = row & 4095;
  const float* src = (i < 2048)
      ? Q + ((size_t)(b * 2048 + i) * 512 + c0)
      : K + ((size_t)(b * 2048 + (i - 2048)) * 512 + c0);
  float4 v0 = ((const float4*)src)[0];
  float4 v1 = ((const float4*)src)[1];
  ushort8 o;
  o[0] = f2bf(v0.x); o[1] = f2bf(v0.y); o[2] = f2bf(v0.z); o[3] = f2bf(v0.w);
  o[4] = f2bf(v1.x); o[5] = f2bf(v1.y); o[6] = f2bf(v1.z); o[7] = f2bf(v1.w);
  *(ushort8*)(Z + (size_t)row * 512 + c0) = o;
}

// ---------------------------------------------------------------------------
// Temporal gram, upper-triangle 256x256 tiles (ri<=cj over 16x16 tile grid),
// 16x16x32 bf16 MFMA, BK=32, 4-deep LDS ring (4 x 32 KB), counted vmcnt
// pipeline (3 K-tiles in flight), raw s_barrier. 512 threads = 8 waves as
// 2(M,128 rows) x 4(N,64 cols); per-wave acc 8x4 fragments.
// LDS per buffer: A [256][32] bf16 (8192 el) then B [256][32] (8192 el).
// Swizzle (verified conflict-free in R7): staging lane chunk kq =
// (l&3)^((l>>3)&3); read chunk swz = q^((lm>>1)&3).
// ---------------------------------------------------------------------------
__global__ __launch_bounds__(512) void temporal_gemm_kernel(
    const unsigned short* __restrict__ Z, float* __restrict__ part) {
  extern __shared__ __align__(16) unsigned short smem[];  // 4*16384 el = 128KB
  int id = blockIdx.x;                  // 0..543
  int x = id & 7;
  int b = x >> 1;                       // XCD-pair lock per batch
  int t = (id >> 3) * 2 + (x & 1);      // 0..135
  // invert t = cj*(cj+1)/2 + ri, ri<=cj (16 tile rows/cols)
  int cj = (int)((sqrtf(8.0f * (float)t + 1.0f) - 1.0f) * 0.5f);
  while ((cj + 1) * (cj + 2) / 2 <= t) cj++;
  while (cj * (cj + 1) / 2 > t) cj--;
  int ri = t - cj * (cj + 1) / 2;
  const unsigned short* Zb = Z + (size_t)b * 4096 * 512;

  int tid = threadIdx.x;
  int w = tid >> 6, lane = tid & 63;
  int wr = w >> 2, wc = w & 3;          // wave grid 2 x 4
  int lm = lane & 15, q = lane >> 4;
  int swz = q ^ ((lm >> 1) & 3);        // frag-read physical chunk

  // Staging: each wave stages 16 rows per load; 4 loads per K-tile
  // (A rows w*16.., A rows 128+w*16.., same for B).
  int srow = w * 16 + (lane >> 2);      // 0..127
  int kq = (lane & 3) ^ ((lane >> 3) & 3);
  const unsigned short* gA0 = Zb + (size_t)(ri * 256 + srow) * 512 + kq * 8;
  const unsigned short* gA1 = gA0 + (size_t)128 * 512;
  const unsigned short* gB0 = Zb + (size_t)(cj * 256 + srow) * 512 + kq * 8;
  const unsigned short* gB1 = gB0 + (size_t)128 * 512;
  int lo0 = (w * 16) * 32;              // wave-uniform LDS element offsets
  int lo1 = (128 + w * 16) * 32;

  f32x4 acc[8][4];
#pragma unroll
  for (int mi = 0; mi < 8; mi++)
#pragma unroll
    for (int ni = 0; ni < 4; ni++) acc[mi][ni] = (f32x4)(0.f);

#define STAGE(kt_)                                                     \
  do {                                                                 \
    unsigned short* base_ = smem + (((kt_) & 3) * 16384);              \
    int go_ = (kt_) * 32;                                              \
    async_cp16(gA0 + go_, base_ + lo0);                                \
    async_cp16(gA1 + go_, base_ + lo1);                                \
    async_cp16(gB0 + go_, base_ + 8192 + lo0);                         \
    async_cp16(gB1 + go_, base_ + 8192 + lo1);                         \
  } while (0)

  // Prologue: 3 K-tiles in flight (12 wave-loads outstanding).
  STAGE(0);
  STAGE(1);
  STAGE(2);

  for (int kt = 0; kt < 16; ++kt) {
    // Issue stage of kt+3 into ring slot (kt-1)&3 — its reads completed
    // before the closing barrier of iteration kt-1.
    if (kt + 3 < 16) STAGE(kt + 3);

    // Wait until kt's 4 loads (oldest) have landed; keep up to 3 K-tiles
    // (12 loads) in flight. Tail tightens as issues stop.
    if (kt < 13)
      asm volatile("s_waitcnt vmcnt(12)" ::: "memory");
    else if (kt == 13)
      asm volatile("s_waitcnt vmcnt(8)" ::: "memory");
    else if (kt == 14)
      asm volatile("s_waitcnt vmcnt(4)" ::: "memory");
    else
      asm volatile("s_waitcnt vmcnt(0)" ::: "memory");
    asm volatile("s_barrier" ::: "memory");  // all waves' kt stages landed

    const unsigned short* A = smem + (kt & 3) * 16384;
    const unsigned short* B = A + 8192;
    short8 af[8], bfr[4];
#pragma unroll
    for (int mi = 0; mi < 8; mi++) {
      int ar = wr * 128 + mi * 16 + lm;
      af[mi] = *(const short8*)(A + ar * 32 + swz * 8);
    }
#pragma unroll
    for (int ni = 0; ni < 4; ni++) {
      int bc = wc * 64 + ni * 16 + lm;
      bfr[ni] = *(const short8*)(B + bc * 32 + swz * 8);
    }
    __builtin_amdgcn_s_setprio(1);
#pragma unroll
    for (int mi = 0; mi < 8; mi++)
#pragma unroll
      for (int ni = 0; ni < 4; ni++)
        acc[mi][ni] = __builtin_amdgcn_mfma_f32_16x16x32_bf16(
            af[mi], bfr[ni], acc[mi][ni], 0, 0, 0);
    __builtin_amdgcn_s_setprio(0);
    // Closing barrier: guarantees all waves' LDS reads of this ring slot
    // are done before any wave issues the stage that overwrites it.
    asm volatile("s_barrier" ::: "memory");
  }
#undef STAGE

  // Epilogue. C/D layout: col=lane&15, row=(lane>>4)*4+reg (m89-verified).
  // Row r (block R=ri): row-slots cj*4+wc (>= 4R), col-slots ri*2+wr (< 2R).
  // Gap slots [2R,4R) are zeroed by convert_bf16.
  float csum[4];
#pragma unroll
  for (int ni = 0; ni < 4; ni++) csum[ni] = 0.f;

#pragma unroll
  for (int mi = 0; mi < 8; mi++) {
    float rs[4];
#pragma unroll
    for (int rr = 0; rr < 4; rr++) rs[rr] = 0.f;
#pragma unroll
    for (int ni = 0; ni < 4; ni++) {
#pragma unroll
      for (int rr = 0; rr < 4; rr++) {
        int R = ri * 256 + wr * 128 + mi * 16 + q * 4 + rr;
        int Cg = cj * 256 + wc * 64 + ni * 16 + lm;
        float e = (R != Cg) ? __expf(acc[mi][ni][rr] - EXP_OFF) : 0.f;
        rs[rr] += e;
        csum[ni] += e;
      }
    }
    // Row-sums: reduce across the 16 lm lanes (q preserved).
#pragma unroll
    for (int rr = 0; rr < 4; rr++) {
      float s = rs[rr];
      s += __shfl_xor(s, 1);
      s += __shfl_xor(s, 2);
      s += __shfl_xor(s, 4);
      s += __shfl_xor(s, 8);
      if (lm == 0) {
        int R = ri * 256 + wr * 128 + mi * 16 + q * 4 + rr;
        part[((size_t)(b * 4096 + R)) * 64 + cj * 4 + wc] = s;
      }
    }
  }

  // Col-sums (off-diagonal tiles only): reduce across the 4 q lanes.
  if (ri != cj) {
#pragma unroll
    for (int ni = 0; ni < 4; ni++) {
      float s = csum[ni];
      s += __shfl_xor(s, 16);
      s += __shfl_xor(s, 32);
      if (q == 0) {
        int Cg = cj * 256 + wc * 64 + ni * 16 + lm;
        part[((size_t)(b * 4096 + Cg)) * 64 + ri * 2 + wr] = s;
      }
    }
  }
}

// lse_temp[row] = 80 + log(sum of 64 partials). One thread per row.
__global__ __launch_bounds__(256) void merge_row_kernel(
    const float* __restrict__ part, float* __restrict__ lse_temp) {
  int row = blockIdx.x * 256 + threadIdx.x;  // 0..16383
  const float4* p = (const float4*)(part + (size_t)row * 64);
  float s = 0.f;
#pragma unroll
  for (int i = 0; i < 16; i++) {
    float4 v = p[i];
    s += v.x + v.y + v.z + v.w;
  }
  lse_temp[row] = EXP_OFF + __logf(s);
}

// ---------------------------------------------------------------------------
// Instance LSE via MFMA: one wave per t-pair; dual accumulator.
// ---------------------------------------------------------------------------
__global__ __launch_bounds__(256) void instance_kernel(
    const unsigned short* __restrict__ Z,
    float* __restrict__ lse_inst /* [2048][8] */,
    float* __restrict__ posdot /* [4][2048] */) {
  int wave = (blockIdx.x * 256 + threadIdx.x) >> 6;  // 0..1023
  int t0 = wave * 2;
  int lane = threadIdx.x & 63;
  int lm = lane & 15, q = lane >> 4;
  int tt = (lm < 8) ? t0 : t0 + 1;
  int v = lm & 7;
  size_t zrow = (v < 4) ? ((size_t)v * 4096 + tt)
                        : ((size_t)(v - 4) * 4096 + 2048 + tt);
  const unsigned short* g = Z + zrow * 512 + q * 8;

  f32x4 acc0 = (f32x4)(0.f), acc1 = (f32x4)(0.f);
#pragma unroll
  for (int kc = 0; kc < 16; kc += 2) {
    short8 a0 = *(const short8*)(g + kc * 32);
    short8 a1 = *(const short8*)(g + kc * 32 + 32);
    acc0 = __builtin_amdgcn_mfma_f32_16x16x32_bf16(a0, a0, acc0, 0, 0, 0);
    acc1 = __builtin_amdgcn_mfma_f32_16x16x32_bf16(a1, a1, acc1, 0, 0, 0);
  }
  f32x4 acc = acc0 + acc1;

#pragma unroll
  for (int rr = 0; rr < 4; rr++) {
    int i = q * 4 + rr;                      // row 0..15
    float val = acc[rr];
    bool samehalf = ((i < 8) == (lm < 8));
    int t = (i < 8) ? t0 : t0 + 1;
    int iv = i & 7;
    if (samehalf && iv < 4 && (lm & 7) == iv + 4)
      posdot[iv * 2048 + t] = val;
    float dd = (samehalf && lm != i) ? val : -INFINITY;
    float mt = dd;
    mt = fmaxf(mt, __shfl_xor(mt, 1));
    mt = fmaxf(mt, __shfl_xor(mt, 2));
    mt = fmaxf(mt, __shfl_xor(mt, 4));
    float e = __expf(dd - mt);
    e += __shfl_xor(e, 1);
    e += __shfl_xor(e, 2);
    e += __shfl_xor(e, 4);
    if ((lm & 7) == 0 && samehalf) lse_inst[t * 8 + iv] = mt + __logf(e);
  }
}

// ---------------------------------------------------------------------------
// Fused combine + top-7. One block; each thread owns 8 t's in registers.
// ---------------------------------------------------------------------------
__global__ __launch_bounds__(256) void combine_topk_kernel(
    const float* __restrict__ lse_inst, const float* __restrict__ lse_temp,
    const float* __restrict__ posdot, int* __restrict__ index_out) {
  __shared__ float wmax[4];
  __shared__ int widx[4];
  int tid = threadIdx.x;
  int base = tid * 8;
  float v[8];
#pragma unroll
  for (int r = 0; r < 8; r++) {
    int t = base + r;
    float sum = 0.f;
#pragma unroll
    for (int b = 0; b < 4; b++) {
      sum += 0.25f * (lse_inst[t * 8 + b] + lse_inst[t * 8 + 4 + b] +
                      lse_temp[b * 4096 + t] + lse_temp[b * 4096 + 2048 + t]) -
             posdot[b * 2048 + t];
    }
    v[r] = sum * 0.25f;
  }
  int lane = tid & 63, w = tid >> 6;
  for (int k = 0; k < 7; k++) {
    float bv = v[0];
    int bi = base;
#pragma unroll
    for (int r = 1; r < 8; r++)
      if (v[r] > bv) { bv = v[r]; bi = base + r; }
#pragma unroll
    for (int d = 1; d < 64; d <<= 1) {
      float ov = __shfl_xor(bv, d);
      int oi = __shfl_xor(bi, d);
      if (ov > bv || (ov == bv && oi < bi)) { bv = ov; bi = oi; }
    }
    if (lane == 0) { wmax[w] = bv; widx[w] = bi; }
    __syncthreads();
    float BV = wmax[0];
    int BI = widx[0];
#pragma unroll
    for (int ww = 1; ww < 4; ww++)
      if (wmax[ww] > BV || (wmax[ww] == BV && widx[ww] < BI)) {
        BV = wmax[ww];
        BI = widx[ww];
      }
    if (tid == 0) index_out[k] = BI;
    if (BI >= base && BI < base + 8) v[BI - base] = -INFINITY;
    __syncthreads();
  }
}

// ---------------------------------------------------------------------------
// Cumsum phase A: per-32-row group sums. grid = 32 bh * 64 groups = 2048
// blocks, 64 threads (1 wave). psum layout: [bh][g][64] floats.
// ---------------------------------------------------------------------------
__global__ __launch_bounds__(64) void cumsum_psum_kernel(
    const float* __restrict__ V, float* __restrict__ psum) {
  int gb = blockIdx.x;              // 0..2047
  int bh = gb >> 6, g = gb & 63;
  int h = bh & 7, b = bh >> 3;
  int lane = threadIdx.x;
  int ro = lane >> 4, e4 = (lane & 15) * 4;
  const float* base =
      V + (size_t)(b * 2048 + g * 32 + ro) * 512 + h * 64 + e4;
  float sx = 0.f, sy = 0.f, sz = 0.f, sw = 0.f;
#pragma unroll
  for (int k = 0; k < 8; k++) {
    float4 v = *(const float4*)(base + (size_t)(k * 4) * 512);
    sx += v.x; sy += v.y; sz += v.z; sw += v.w;
  }
  sx += __shfl_xor(sx, 16); sy += __shfl_xor(sy, 16);
  sz += __shfl_xor(sz, 16); sw += __shfl_xor(sw, 16);
  sx += __shfl_xor(sx, 32); sy += __shfl_xor(sy, 32);
  sz += __shfl_xor(sz, 32); sw += __shfl_xor(sw, 32);
  if (ro == 0) {
    float4 o = {sx, sy, sz, sw};
    *(float4*)(psum + ((size_t)bh * 64 + g) * 64 + e4) = o;
  }
}

// ---------------------------------------------------------------------------
// Cumsum phase B: scan + write. grid = 32 bh * 16 chunks = 512 blocks.
// ---------------------------------------------------------------------------
__global__ __launch_bounds__(256) void cumsum_write_kernel(
    const float* __restrict__ V, const float* __restrict__ psum,
    const int* __restrict__ index, float* __restrict__ out) {
  int blk = blockIdx.x;             // 0..511
  int bh = blk >> 4, chunk = blk & 15;
  int h = bh & 7, b = bh >> 3;
  int tid = threadIdx.x;
  int e = tid & 63, sub = tid >> 6;
  int g = chunk * 4 + sub;          // 0..63

  const float* ps = psum + (size_t)bh * 64 * 64;
  float run = 0.f;
  for (int gg = 0; gg < g; ++gg) run += ps[gg * 64 + e];

  int idx[7];
#pragma unroll
  for (int k = 0; k < 7; k++) idx[k] = index[k];

  const float* Vbase = V + (size_t)(b * 2048) * 512 + h * 64 + e;
  float* obase = out + (size_t)bh * 2048 * 64 + e;

  int l0 = g * 32;
#pragma unroll 4
  for (int l = l0; l < l0 + 32; ++l) {
    run += Vbase[(size_t)l * 512];
    float o = run;
    bool special = false;
#pragma unroll
    for (int k = 0; k < 7; k++) special = special || (idx[k] == l);
    if (special) o = run / (float)(l + 1);
    obase[(size_t)l * 64] = o;
  }
}

extern "C" void kernel_launch(void* const* d_in, const int* in_sizes, int n_in,
                              void* d_out, int out_size, void* d_ws, size_t ws_size,
                              hipStream_t stream) {
  const float* Q = (const float*)d_in[0];  // (4,2048,512)
  const float* K = (const float*)d_in[1];
  const float* V = (const float*)d_in[2];
  float* out = (float*)d_out;              // (4,8,2048,64)

  // Workspace layout:
  unsigned short* Z = (unsigned short*)d_ws;        // 4*4096*512 bf16 = 16.8 MB
  float* base = (float*)d_ws + 4 * 4096 * 512 / 2;  // after Z
  float* part = base;                               // 4*4096*64 = 1M floats
  float* lse_t = base + 4 * 4096 * 64;              // 16384
  float* lse_i = lse_t + 16384;                     // 16384
  float* posd = lse_i + 16384;                      // 8192
  int* idx = (int*)(posd + 8192);                   // 8
  float* psum = part;  // 32*64*64 floats = 512 KB, reuses dead `part`

  static bool attr_set = false;
  if (!attr_set) {
    hipFuncSetAttribute((const void*)temporal_gemm_kernel,
                        hipFuncAttributeMaxDynamicSharedMemorySize, 131072);
    attr_set = true;
  }

  convert_bf16_kernel<<<4096, 256, 0, stream>>>(Q, K, Z, part);
  temporal_gemm_kernel<<<544, 512, 131072, stream>>>(Z, part);
  instance_kernel<<<256, 256, 0, stream>>>(Z, lse_i, posd);
  merge_row_kernel<<<64, 256, 0, stream>>>(part, lse_t);
  combine_topk_kernel<<<1, 256, 0, stream>>>(lse_i, lse_t, posd, idx);
  // part is dead after merge_row; safe to overlay psum.
  cumsum_psum_kernel<<<2048, 64, 0, stream>>>(V, psum);
  cumsum_write_kernel<<<512, 256, 0, stream>>>(V, psum, idx, out);
}

// Round 3
// 199.912 us; speedup vs baseline: 1.0384x; 1.0384x over previous
//
#include <hip/hip_runtime.h>
#include <math.h>

// Problem constants: B=4, L=T=2048, H=8, E=64, C=H*E=512, top_k=7
// Output = cumsum(V) with top-7 rows (by corrmean) replaced by running mean.
// Only the top-7 index SET of corrmean affects the output -> grams in bf16
// MFMA. Temporal LSE uses fixed exp-offset 80; sum-only partials.
// R6: symmetric gram -> upper-triangle tiles only.
// R9: cumsum split into full-GPU psum+write phases.
// R10: coarse counted-vmcnt 256x256 ring -> REGRESSED (72.6us, MfmaUtil 19%).
//     Lesson: coarse phase-split without fine interleave is the m196
//     anti-pattern.
// R11 (this round): faithful m201-style 8-phase schedule. 256x256, BK=64,
//     2 K-tiles/iter, 8 phases/iter; phase = {4-12 ds_read || stage one
//     half-tile (2 gload_lds) -> s_barrier -> lgkmcnt(0) -> setprio ->
//     16 MFMA (one quadrant x K=64) -> s_barrier}. vmcnt(4) only at
//     phases 3/7 before the closing barrier. Stage schedule (dest dead at
//     issue, verified vs barrier pairing): p0/p1 A(kt1), p2/p3 B(kt0+2),
//     p4/p5 A(kt0+2), p6/p7 B(kt1+2); tail wraps kt&7 (harmless re-stage).
//     R7's chunk-XOR swizzle reused verbatim per 128x32 LDS block.

typedef __attribute__((ext_vector_type(8))) short short8;
typedef __attribute__((ext_vector_type(8))) unsigned short ushort8;
typedef __attribute__((ext_vector_type(4))) float f32x4;

typedef const __attribute__((address_space(1))) void* gas_ptr;
typedef __attribute__((address_space(3))) void* las_ptr;

#define EXP_OFF 80.0f

__device__ __forceinline__ void async_cp16(const void* g, void* l) {
  // LDS dest is wave-uniform base; HW adds lane*16 (m104/m108).
  __builtin_amdgcn_global_load_lds((gas_ptr)g, (las_ptr)l, 16, 0, 0);
}

__device__ __forceinline__ unsigned short f2bf(float x) {
  union { float f; unsigned int u; } v; v.f = x;
  unsigned int r = v.u + 0x7FFFu + ((v.u >> 16) & 1u);  // RNE
  return (unsigned short)(r >> 16);
}

// ---------------------------------------------------------------------------
// Convert Q,K fp32 -> Z bf16 [4][4096][512] (rows 0..2047 = Q, 2048.. = K).
// Also zero-fills part[1048576] (one float per thread) so the temporal
// epilogue's unused slots read as 0 in merge_row.
// ---------------------------------------------------------------------------
__global__ __launch_bounds__(256) void convert_bf16_kernel(
    const float* __restrict__ Q, const float* __restrict__ K,
    unsigned short* __restrict__ Z, float* __restrict__ part) {
  int tid = blockIdx.x * 256 + threadIdx.x;  // 0..1048575
  part[tid] = 0.f;                           // part = 4*4096*64 floats exactly
  int row = tid >> 6;                        // b*4096 + i
  int c0 = (tid & 63) * 8;
  int b = row >> 12, i = row & 4095;
  const float* src = (i < 2048)
      ? Q + ((size_t)(b * 2048 + i) * 512 + c0)
      : K + ((size_t)(b * 2048 + (i - 2048)) * 512 + c0);
  float4 v0 = ((const float4*)src)[0];
  float4 v1 = ((const float4*)src)[1];
  ushort8 o;
  o[0] = f2bf(v0.x); o[1] = f2bf(v0.y); o[2] = f2bf(v0.z); o[3] = f2bf(v0.w);
  o[4] = f2bf(v1.x); o[5] = f2bf(v1.y); o[6] = f2bf(v1.z); o[7] = f2bf(v1.w);
  *(ushort8*)(Z + (size_t)row * 512 + c0) = o;
}

// ---------------------------------------------------------------------------
// Temporal gram, upper-triangle 256x256 tiles (ri<=cj over 16x16 tile grid),
// 16x16x32 bf16 MFMA, 8-phase m201-style schedule.
// 512 threads = 8 waves as 2(M,128 rows) x 4(N,64 cols); per-wave acc 8x4.
// LDS: 2 slots x { A: [2 rowhalf][2 khalf][128][32], B: same } = 128 KB.
// Block (h,kh) = 128x32 el, R7 chunk-XOR swizzled (bank-conflict-0).
// ---------------------------------------------------------------------------
__global__ __launch_bounds__(512) void temporal_gemm_kernel(
    const unsigned short* __restrict__ Z, float* __restrict__ part) {
  extern __shared__ __align__(16) unsigned short smem[];  // 65536 el = 128KB
  int id = blockIdx.x;                  // 0..543
  int x = id & 7;
  int b = x >> 1;                       // XCD-pair lock per batch
  int t = (id >> 3) * 2 + (x & 1);      // 0..135
  // invert t = cj*(cj+1)/2 + ri, ri<=cj (16 tile rows/cols)
  int cj = (int)((sqrtf(8.0f * (float)t + 1.0f) - 1.0f) * 0.5f);
  while ((cj + 1) * (cj + 2) / 2 <= t) cj++;
  while (cj * (cj + 1) / 2 > t) cj--;
  int ri = t - cj * (cj + 1) / 2;
  const unsigned short* Zb = Z + (size_t)b * 4096 * 512;

  int tid = threadIdx.x;
  int w = tid >> 6, lane = tid & 63;
  int wr = w >> 2, wc = w & 3;          // wave grid 2 x 4
  int lm = lane & 15, q = lane >> 4;
  int swz = q ^ ((lm >> 1) & 3);        // frag-read physical chunk

  // Staging (R7-verified): 16 rows x 32 el per wave-issue; lane l -> row
  // l>>2, phys chunk l&3 holding logical chunk (l&3)^((l>>3)&3).
  int srow = w * 16 + (lane >> 2);      // 0..127 across the 8 waves
  int kq = (lane & 3) ^ ((lane >> 3) & 3);
  const unsigned short* gA = Zb + (size_t)(ri * 256 + srow) * 512 + kq * 8;
  const unsigned short* gB = Zb + (size_t)(cj * 256 + srow) * 512 + kq * 8;

  // LDS element offsets:  slot*32768 + mat(0|16384) + h*8192 + kh*4096
  //                       + row*32 + chunk*8
  // Frag-read bases (add slot*32768 + kh*4096 + mi_or_ni*512):
  const unsigned short* abase = smem + wr * 8192 + lm * 32 + swz * 8;
  const unsigned short* bbase =
      smem + 16384 + (wc >> 1) * 8192 + ((wc & 1) * 64 + lm) * 32 + swz * 8;

  f32x4 acc[8][4];
#pragma unroll
  for (int mi = 0; mi < 8; mi++)
#pragma unroll
    for (int ni = 0; ni < 4; ni++) acc[mi][ni] = (f32x4)(0.f);

  // Stage one half-tile (matrix mat, rowhalf h) of K-tile kt: 2 issues.
#define STG(gbase, matoff, kt, h)                                          \
  do {                                                                     \
    const unsigned short* s_ =                                             \
        (gbase) + (size_t)(h) * 65536 + (((kt) & 7) * 64);                 \
    unsigned short* d_ =                                                   \
        smem + (((kt) & 1) * 32768) + (matoff) + (h) * 8192 + w * 512;     \
    async_cp16(s_, d_);          /* kh = 0 */                              \
    async_cp16(s_ + 32, d_ + 4096); /* kh = 1 */                           \
  } while (0)

  // Prologue: A(0), B(0) (slot 0), B(1) (slot 1) = 12 issues.
  STG(gA, 0, 0, 0);
  STG(gA, 0, 0, 1);
  STG(gB, 16384, 0, 0);
  STG(gB, 16384, 0, 1);
  STG(gB, 16384, 1, 0);
  STG(gB, 16384, 1, 1);
  asm volatile("s_waitcnt vmcnt(4)" ::: "memory");  // A(0)+B(0) landed
  asm volatile("s_barrier" ::: "memory");

  short8 bfr[4][2];  // B frags persist across the 4 phases of a K-tile

  for (int it = 0; it < 4; ++it) {
    int kt0 = 2 * it, kt1 = 2 * it + 1;
#pragma unroll
    for (int ph = 0; ph < 8; ++ph) {
      const int s = ph >> 2;              // slot: 0 for p0-3, 1 for p4-7
      const int mi0 = (ph & 3) * 2;       // quadrant mi base
      // --- ds reads (current slot; data gated at an earlier vmcnt+bar) ---
      if ((ph & 3) == 0) {
#pragma unroll
        for (int ni = 0; ni < 4; ni++)
#pragma unroll
          for (int kh = 0; kh < 2; kh++)
            bfr[ni][kh] = *(const short8*)(bbase + s * 32768 + kh * 4096 +
                                           ni * 512);
      }
      short8 a00 = *(const short8*)(abase + s * 32768 + 0 * 4096 + mi0 * 512);
      short8 a01 = *(const short8*)(abase + s * 32768 + 1 * 4096 + mi0 * 512);
      short8 a10 =
          *(const short8*)(abase + s * 32768 + 0 * 4096 + (mi0 + 1) * 512);
      short8 a11 =
          *(const short8*)(abase + s * 32768 + 1 * 4096 + (mi0 + 1) * 512);
      // --- stage one half-tile (dest region dead; see header comment) ---
      switch (ph) {
        case 0: STG(gA, 0, kt1, 0); break;
        case 1: STG(gA, 0, kt1, 1); break;
        case 2: STG(gB, 16384, kt0 + 2, 0); break;
        case 3: STG(gB, 16384, kt0 + 2, 1); break;
        case 4: STG(gA, 0, kt0 + 2, 0); break;
        case 5: STG(gA, 0, kt0 + 2, 1); break;
        case 6: STG(gB, 16384, kt1 + 2, 0); break;
        case 7: STG(gB, 16384, kt1 + 2, 1); break;
      }
      asm volatile("s_barrier" ::: "memory");
      asm volatile("s_waitcnt lgkmcnt(0)" ::: "memory");
      __builtin_amdgcn_s_setprio(1);
#pragma unroll
      for (int ni = 0; ni < 4; ni++) {
        acc[mi0][ni] = __builtin_amdgcn_mfma_f32_16x16x32_bf16(
            a00, bfr[ni][0], acc[mi0][ni], 0, 0, 0);
        acc[mi0][ni] = __builtin_amdgcn_mfma_f32_16x16x32_bf16(
            a01, bfr[ni][1], acc[mi0][ni], 0, 0, 0);
        acc[mi0 + 1][ni] = __builtin_amdgcn_mfma_f32_16x16x32_bf16(
            a10, bfr[ni][0], acc[mi0 + 1][ni], 0, 0, 0);
        acc[mi0 + 1][ni] = __builtin_amdgcn_mfma_f32_16x16x32_bf16(
            a11, bfr[ni][1], acc[mi0 + 1][ni], 0, 0, 0);
      }
      __builtin_amdgcn_s_setprio(0);
      if ((ph & 3) == 3)  // once per K-tile: gate the next slot's A through
        asm volatile("s_waitcnt vmcnt(4)" ::: "memory");
      asm volatile("s_barrier" ::: "memory");
    }
  }
#undef STG
  asm volatile("s_waitcnt vmcnt(0)" ::: "memory");  // drain wrapped stages

  // Epilogue. C/D layout: col=lane&15, row=(lane>>4)*4+reg (m89-verified).
  // Row-slots cj*4+wc (>= 4R), col-slots ri*2+wr (< 2R); gaps zeroed by
  // convert_bf16.
  float csum[4];
#pragma unroll
  for (int ni = 0; ni < 4; ni++) csum[ni] = 0.f;

#pragma unroll
  for (int mi = 0; mi < 8; mi++) {
    float rs[4];
#pragma unroll
    for (int rr = 0; rr < 4; rr++) rs[rr] = 0.f;
#pragma unroll
    for (int ni = 0; ni < 4; ni++) {
#pragma unroll
      for (int rr = 0; rr < 4; rr++) {
        int R = ri * 256 + wr * 128 + mi * 16 + q * 4 + rr;
        int Cg = cj * 256 + wc * 64 + ni * 16 + lm;
        float e = (R != Cg) ? __expf(acc[mi][ni][rr] - EXP_OFF) : 0.f;
        rs[rr] += e;
        csum[ni] += e;
      }
    }
#pragma unroll
    for (int rr = 0; rr < 4; rr++) {
      float s = rs[rr];
      s += __shfl_xor(s, 1);
      s += __shfl_xor(s, 2);
      s += __shfl_xor(s, 4);
      s += __shfl_xor(s, 8);
      if (lm == 0) {
        int R = ri * 256 + wr * 128 + mi * 16 + q * 4 + rr;
        part[((size_t)(b * 4096 + R)) * 64 + cj * 4 + wc] = s;
      }
    }
  }

  if (ri != cj) {
#pragma unroll
    for (int ni = 0; ni < 4; ni++) {
      float s = csum[ni];
      s += __shfl_xor(s, 16);
      s += __shfl_xor(s, 32);
      if (q == 0) {
        int Cg = cj * 256 + wc * 64 + ni * 16 + lm;
        part[((size_t)(b * 4096 + Cg)) * 64 + ri * 2 + wr] = s;
      }
    }
  }
}

// lse_temp[row] = 80 + log(sum of 64 partials). One thread per row.
__global__ __launch_bounds__(256) void merge_row_kernel(
    const float* __restrict__ part, float* __restrict__ lse_temp) {
  int row = blockIdx.x * 256 + threadIdx.x;  // 0..16383
  const float4* p = (const float4*)(part + (size_t)row * 64);
  float s = 0.f;
#pragma unroll
  for (int i = 0; i < 16; i++) {
    float4 v = p[i];
    s += v.x + v.y + v.z + v.w;
  }
  lse_temp[row] = EXP_OFF + __logf(s);
}

// ---------------------------------------------------------------------------
// Instance LSE via MFMA: one wave per t-pair; dual accumulator.
// ---------------------------------------------------------------------------
__global__ __launch_bounds__(256) void instance_kernel(
    const unsigned short* __restrict__ Z,
    float* __restrict__ lse_inst /* [2048][8] */,
    float* __restrict__ posdot /* [4][2048] */) {
  int wave = (blockIdx.x * 256 + threadIdx.x) >> 6;  // 0..1023
  int t0 = wave * 2;
  int lane = threadIdx.x & 63;
  int lm = lane & 15, q = lane >> 4;
  int tt = (lm < 8) ? t0 : t0 + 1;
  int v = lm & 7;
  size_t zrow = (v < 4) ? ((size_t)v * 4096 + tt)
                        : ((size_t)(v - 4) * 4096 + 2048 + tt);
  const unsigned short* g = Z + zrow * 512 + q * 8;

  f32x4 acc0 = (f32x4)(0.f), acc1 = (f32x4)(0.f);
#pragma unroll
  for (int kc = 0; kc < 16; kc += 2) {
    short8 a0 = *(const short8*)(g + kc * 32);
    short8 a1 = *(const short8*)(g + kc * 32 + 32);
    acc0 = __builtin_amdgcn_mfma_f32_16x16x32_bf16(a0, a0, acc0, 0, 0, 0);
    acc1 = __builtin_amdgcn_mfma_f32_16x16x32_bf16(a1, a1, acc1, 0, 0, 0);
  }
  f32x4 acc = acc0 + acc1;

#pragma unroll
  for (int rr = 0; rr < 4; rr++) {
    int i = q * 4 + rr;                      // row 0..15
    float val = acc[rr];
    bool samehalf = ((i < 8) == (lm < 8));
    int t = (i < 8) ? t0 : t0 + 1;
    int iv = i & 7;
    if (samehalf && iv < 4 && (lm & 7) == iv + 4)
      posdot[iv * 2048 + t] = val;
    float dd = (samehalf && lm != i) ? val : -INFINITY;
    float mt = dd;
    mt = fmaxf(mt, __shfl_xor(mt, 1));
    mt = fmaxf(mt, __shfl_xor(mt, 2));
    mt = fmaxf(mt, __shfl_xor(mt, 4));
    float e = __expf(dd - mt);
    e += __shfl_xor(e, 1);
    e += __shfl_xor(e, 2);
    e += __shfl_xor(e, 4);
    if ((lm & 7) == 0 && samehalf) lse_inst[t * 8 + iv] = mt + __logf(e);
  }
}

// ---------------------------------------------------------------------------
// Fused combine + top-7. One block; each thread owns 8 t's in registers.
// ---------------------------------------------------------------------------
__global__ __launch_bounds__(256) void combine_topk_kernel(
    const float* __restrict__ lse_inst, const float* __restrict__ lse_temp,
    const float* __restrict__ posdot, int* __restrict__ index_out) {
  __shared__ float wmax[4];
  __shared__ int widx[4];
  int tid = threadIdx.x;
  int base = tid * 8;
  float v[8];
#pragma unroll
  for (int r = 0; r < 8; r++) {
    int t = base + r;
    float sum = 0.f;
#pragma unroll
    for (int b = 0; b < 4; b++) {
      sum += 0.25f * (lse_inst[t * 8 + b] + lse_inst[t * 8 + 4 + b] +
                      lse_temp[b * 4096 + t] + lse_temp[b * 4096 + 2048 + t]) -
             posdot[b * 2048 + t];
    }
    v[r] = sum * 0.25f;
  }
  int lane = tid & 63, w = tid >> 6;
  for (int k = 0; k < 7; k++) {
    float bv = v[0];
    int bi = base;
#pragma unroll
    for (int r = 1; r < 8; r++)
      if (v[r] > bv) { bv = v[r]; bi = base + r; }
#pragma unroll
    for (int d = 1; d < 64; d <<= 1) {
      float ov = __shfl_xor(bv, d);
      int oi = __shfl_xor(bi, d);
      if (ov > bv || (ov == bv && oi < bi)) { bv = ov; bi = oi; }
    }
    if (lane == 0) { wmax[w] = bv; widx[w] = bi; }
    __syncthreads();
    float BV = wmax[0];
    int BI = widx[0];
#pragma unroll
    for (int ww = 1; ww < 4; ww++)
      if (wmax[ww] > BV || (wmax[ww] == BV && widx[ww] < BI)) {
        BV = wmax[ww];
        BI = widx[ww];
      }
    if (tid == 0) index_out[k] = BI;
    if (BI >= base && BI < base + 8) v[BI - base] = -INFINITY;
    __syncthreads();
  }
}

// ---------------------------------------------------------------------------
// Cumsum phase A: per-32-row group sums. grid = 32 bh * 64 groups = 2048
// blocks, 64 threads (1 wave). psum layout: [bh][g][64] floats.
// ---------------------------------------------------------------------------
__global__ __launch_bounds__(64) void cumsum_psum_kernel(
    const float* __restrict__ V, float* __restrict__ psum) {
  int gb = blockIdx.x;              // 0..2047
  int bh = gb >> 6, g = gb & 63;
  int h = bh & 7, b = bh >> 3;
  int lane = threadIdx.x;
  int ro = lane >> 4, e4 = (lane & 15) * 4;
  const float* base =
      V + (size_t)(b * 2048 + g * 32 + ro) * 512 + h * 64 + e4;
  float sx = 0.f, sy = 0.f, sz = 0.f, sw = 0.f;
#pragma unroll
  for (int k = 0; k < 8; k++) {
    float4 v = *(const float4*)(base + (size_t)(k * 4) * 512);
    sx += v.x; sy += v.y; sz += v.z; sw += v.w;
  }
  sx += __shfl_xor(sx, 16); sy += __shfl_xor(sy, 16);
  sz += __shfl_xor(sz, 16); sw += __shfl_xor(sw, 16);
  sx += __shfl_xor(sx, 32); sy += __shfl_xor(sy, 32);
  sz += __shfl_xor(sz, 32); sw += __shfl_xor(sw, 32);
  if (ro == 0) {
    float4 o = {sx, sy, sz, sw};
    *(float4*)(psum + ((size_t)bh * 64 + g) * 64 + e4) = o;
  }
}

// ---------------------------------------------------------------------------
// Cumsum phase B: scan + write. grid = 32 bh * 16 chunks = 512 blocks.
// ---------------------------------------------------------------------------
__global__ __launch_bounds__(256) void cumsum_write_kernel(
    const float* __restrict__ V, const float* __restrict__ psum,
    const int* __restrict__ index, float* __restrict__ out) {
  int blk = blockIdx.x;             // 0..511
  int bh = blk >> 4, chunk = blk & 15;
  int h = bh & 7, b = bh >> 3;
  int tid = threadIdx.x;
  int e = tid & 63, sub = tid >> 6;
  int g = chunk * 4 + sub;          // 0..63

  const float* ps = psum + (size_t)bh * 64 * 64;
  float run = 0.f;
  for (int gg = 0; gg < g; ++gg) run += ps[gg * 64 + e];

  int idx[7];
#pragma unroll
  for (int k = 0; k < 7; k++) idx[k] = index[k];

  const float* Vbase = V + (size_t)(b * 2048) * 512 + h * 64 + e;
  float* obase = out + (size_t)bh * 2048 * 64 + e;

  int l0 = g * 32;
#pragma unroll 4
  for (int l = l0; l < l0 + 32; ++l) {
    run += Vbase[(size_t)l * 512];
    float o = run;
    bool special = false;
#pragma unroll
    for (int k = 0; k < 7; k++) special = special || (idx[k] == l);
    if (special) o = run / (float)(l + 1);
    obase[(size_t)l * 64] = o;
  }
}

extern "C" void kernel_launch(void* const* d_in, const int* in_sizes, int n_in,
                              void* d_out, int out_size, void* d_ws, size_t ws_size,
                              hipStream_t stream) {
  const float* Q = (const float*)d_in[0];  // (4,2048,512)
  const float* K = (const float*)d_in[1];
  const float* V = (const float*)d_in[2];
  float* out = (float*)d_out;              // (4,8,2048,64)

  // Workspace layout:
  unsigned short* Z = (unsigned short*)d_ws;        // 4*4096*512 bf16 = 16.8 MB
  float* base = (float*)d_ws + 4 * 4096 * 512 / 2;  // after Z
  float* part = base;                               // 4*4096*64 = 1M floats
  float* lse_t = base + 4 * 4096 * 64;              // 16384
  float* lse_i = lse_t + 16384;                     // 16384
  float* posd = lse_i + 16384;                      // 8192
  int* idx = (int*)(posd + 8192);                   // 8
  float* psum = part;  // 32*64*64 floats = 512 KB, reuses dead `part`

  static bool attr_set = false;
  if (!attr_set) {
    hipFuncSetAttribute((const void*)temporal_gemm_kernel,
                        hipFuncAttributeMaxDynamicSharedMemorySize, 131072);
    attr_set = true;
  }

  convert_bf16_kernel<<<4096, 256, 0, stream>>>(Q, K, Z, part);
  temporal_gemm_kernel<<<544, 512, 131072, stream>>>(Z, part);
  instance_kernel<<<256, 256, 0, stream>>>(Z, lse_i, posd);
  merge_row_kernel<<<64, 256, 0, stream>>>(part, lse_t);
  combine_topk_kernel<<<1, 256, 0, stream>>>(lse_i, lse_t, posd, idx);
  // part is dead after merge_row; safe to overlay psum.
  cumsum_psum_kernel<<<2048, 64, 0, stream>>>(V, psum);
  cumsum_write_kernel<<<512, 256, 0, stream>>>(V, psum, idx, out);
}

// Round 4
// 196.358 us; speedup vs baseline: 1.0572x; 1.0181x over previous
//
#include <hip/hip_runtime.h>
#include <math.h>

// Problem constants: B=4, L=T=2048, H=8, E=64, C=H*E=512, top_k=7
// Output = cumsum(V) with top-7 rows (by corrmean) replaced by running mean.
// Only the top-7 index SET of corrmean affects the output -> grams in bf16
// MFMA. Temporal LSE uses fixed exp-offset 80; sum-only partials.
// R6: symmetric gram -> upper-triangle tiles only (528/1024 per batch).
// R9: cumsum split into full-GPU psum+write phases.
// R10/R11: 256x256 deep-pipeline attempts REGRESSED (72.6 / 66.8 us vs R7's
//     59.2). Lesson: K=512 has only 8 K-tiles -> fill/drain dominates the
//     m201-style schedule; 128KB LDS forces 1 block/CU. Out of regime.
// R12 (this round): revert to the verified R7 128x128 structure and attack
//     its measured limiter (occupancy 25%, VGPR 80 + 64 AGPR = 144 regs ->
//     2-3 blocks/CU): __launch_bounds__(256,4) targets <=128 combined regs
//     -> 4 blocks/CU. Plus two makespan fusions: instance into temporal's
//     grid tail (blocks >= 2112), cumsum_psum into combine's launch
//     (blocks >= 1). 5 launches total.

typedef __attribute__((ext_vector_type(8))) short short8;
typedef __attribute__((ext_vector_type(8))) unsigned short ushort8;
typedef __attribute__((ext_vector_type(4))) float f32x4;

typedef const __attribute__((address_space(1))) void* gas_ptr;
typedef __attribute__((address_space(3))) void* las_ptr;

#define EXP_OFF 80.0f

__device__ __forceinline__ void async_cp16(const void* g, void* l) {
  // LDS dest is wave-uniform base; HW adds lane*16 (m104/m108).
  __builtin_amdgcn_global_load_lds((gas_ptr)g, (las_ptr)l, 16, 0, 0);
}

__device__ __forceinline__ unsigned short f2bf(float x) {
  union { float f; unsigned int u; } v; v.f = x;
  unsigned int r = v.u + 0x7FFFu + ((v.u >> 16) & 1u);  // RNE
  return (unsigned short)(r >> 16);
}

// ---------------------------------------------------------------------------
// Convert Q,K fp32 -> Z bf16 [4][4096][512] (rows 0..2047 = Q, 2048.. = K)
// ---------------------------------------------------------------------------
__global__ __launch_bounds__(256) void convert_bf16_kernel(
    const float* __restrict__ Q, const float* __restrict__ K,
    unsigned short* __restrict__ Z) {
  int tid = blockIdx.x * 256 + threadIdx.x;  // 0..1048575
  int row = tid >> 6;                        // b*4096 + i
  int c0 = (tid & 63) * 8;
  int b = row >> 12, i = row & 4095;
  const float* src = (i < 2048)
      ? Q + ((size_t)(b * 2048 + i) * 512 + c0)
      : K + ((size_t)(b * 2048 + (i - 2048)) * 512 + c0);
  float4 v0 = ((const float4*)src)[0];
  float4 v1 = ((const float4*)src)[1];
  ushort8 o;
  o[0] = f2bf(v0.x); o[1] = f2bf(v0.y); o[2] = f2bf(v0.z); o[3] = f2bf(v0.w);
  o[4] = f2bf(v1.x); o[5] = f2bf(v1.y); o[6] = f2bf(v1.z); o[7] = f2bf(v1.w);
  *(ushort8*)(Z + (size_t)row * 512 + c0) = o;
}

// ---------------------------------------------------------------------------
// Temporal gram (blocks 0..2111): upper-triangle 128x128 tiles (ri<=cj over
// 32x32 tile grid), 16x16x32 bf16 MFMA, BK=32, double-buffered LDS (one
// barrier per kc), XOR-swizzled staging (bank-conflict 0 verified).
// XCD-pair swizzle: b=(id&7)>>1. Epilogue: e=exp(v-80) feeds row-sums
// (slot cj*2+wc) and, off-diagonal, col-sums (slot ri*2+wr) -- slot union
// [0,64) complete per row, no zero-fill needed.
// Blocks 2112..2367: fused instance-LSE path (reads Z only; writes
// lse_inst/posdot -- disjoint from part).
// ---------------------------------------------------------------------------
__global__ __launch_bounds__(256, 4) void temporal_gemm_kernel(
    const unsigned short* __restrict__ Z, float* __restrict__ part,
    float* __restrict__ lse_inst /* [2048][8] */,
    float* __restrict__ posdot /* [4][2048] */) {
  __shared__ __align__(16) unsigned short As[2][128 * 32];  // 2 x 8 KB
  __shared__ __align__(16) unsigned short Bs[2][128 * 32];  // 2 x 8 KB

  if (blockIdx.x >= 2112) {
    // ---------------- instance path (was instance_kernel) ----------------
    int wave = ((blockIdx.x - 2112) * 256 + threadIdx.x) >> 6;  // 0..1023
    int t0 = wave * 2;
    int lane = threadIdx.x & 63;
    int lm = lane & 15, q = lane >> 4;
    int tt = (lm < 8) ? t0 : t0 + 1;
    int v = lm & 7;
    size_t zrow = (v < 4) ? ((size_t)v * 4096 + tt)
                          : ((size_t)(v - 4) * 4096 + 2048 + tt);
    const unsigned short* g = Z + zrow * 512 + q * 8;

    f32x4 acc0 = (f32x4)(0.f), acc1 = (f32x4)(0.f);
#pragma unroll
    for (int kc = 0; kc < 16; kc += 2) {
      short8 a0 = *(const short8*)(g + kc * 32);
      short8 a1 = *(const short8*)(g + kc * 32 + 32);
      acc0 = __builtin_amdgcn_mfma_f32_16x16x32_bf16(a0, a0, acc0, 0, 0, 0);
      acc1 = __builtin_amdgcn_mfma_f32_16x16x32_bf16(a1, a1, acc1, 0, 0, 0);
    }
    f32x4 acc = acc0 + acc1;

#pragma unroll
    for (int rr = 0; rr < 4; rr++) {
      int i = q * 4 + rr;                      // row 0..15
      float val = acc[rr];
      bool samehalf = ((i < 8) == (lm < 8));
      int t = (i < 8) ? t0 : t0 + 1;
      int iv = i & 7;
      if (samehalf && iv < 4 && (lm & 7) == iv + 4)
        posdot[iv * 2048 + t] = val;
      float dd = (samehalf && lm != i) ? val : -INFINITY;
      float mt = dd;
      mt = fmaxf(mt, __shfl_xor(mt, 1));
      mt = fmaxf(mt, __shfl_xor(mt, 2));
      mt = fmaxf(mt, __shfl_xor(mt, 4));
      float e = __expf(dd - mt);
      e += __shfl_xor(e, 1);
      e += __shfl_xor(e, 2);
      e += __shfl_xor(e, 4);
      if ((lm & 7) == 0 && samehalf) lse_inst[t * 8 + iv] = mt + __logf(e);
    }
    return;
  }

  // ------------------------- gram path (R7) -------------------------------
  int id = blockIdx.x;                  // 0..2111
  int x = id & 7;
  int b = x >> 1;                       // XCD-pair lock per batch
  int t = (id >> 3) * 2 + (x & 1);      // 0..527
  // invert t = cj*(cj+1)/2 + ri, ri<=cj
  int cj = (int)((sqrtf(8.0f * (float)t + 1.0f) - 1.0f) * 0.5f);
  while ((cj + 1) * (cj + 2) / 2 <= t) cj++;
  while (cj * (cj + 1) / 2 > t) cj--;
  int ri = t - cj * (cj + 1) / 2;
  const unsigned short* Zb = Z + (size_t)b * 4096 * 512;

  int tid = threadIdx.x;
  int w = tid >> 6, lane = tid & 63;
  int wr = w >> 1, wc = w & 1;
  int lm = lane & 15, q = lane >> 4;
  int swz = q ^ ((lm >> 1) & 3);  // frag-read physical chunk

  // Staging: slot row = w*16 + (lane>>2), physical chunk lane&3 holds
  // logical chunk kq = (lane&3)^((lane>>3)&3)
  int srow = lane >> 2;
  int kq = (lane & 3) ^ ((lane >> 3) & 3);
  int rl0 = w * 16 + srow;
  int rl1 = 64 + rl0;
  const unsigned short* gA0 = Zb + (size_t)(ri * 128 + rl0) * 512 + kq * 8;
  const unsigned short* gA1 = Zb + (size_t)(ri * 128 + rl1) * 512 + kq * 8;
  const unsigned short* gB0 = Zb + (size_t)(cj * 128 + rl0) * 512 + kq * 8;
  const unsigned short* gB1 = Zb + (size_t)(cj * 128 + rl1) * 512 + kq * 8;
  int lo0 = (w * 16) * 32;        // wave-uniform base offsets
  int lo1 = (64 + w * 16) * 32;

  f32x4 acc[4][4];
#pragma unroll
  for (int mi = 0; mi < 4; mi++)
#pragma unroll
    for (int ni = 0; ni < 4; ni++) acc[mi][ni] = (f32x4)(0.f);

  // Prologue: stage kc=0 into buffer 0.
  async_cp16(gA0, As[0] + lo0);
  async_cp16(gA1, As[0] + lo1);
  async_cp16(gB0, Bs[0] + lo0);
  async_cp16(gB1, Bs[0] + lo1);

  for (int kc = 0; kc < 16; ++kc) {
    int cur = kc & 1;
    __syncthreads();  // drains stage(kc) — issued one compute phase ago

    if (kc < 15) {
      int go = (kc + 1) * 32;
      async_cp16(gA0 + go, As[cur ^ 1] + lo0);
      async_cp16(gA1 + go, As[cur ^ 1] + lo1);
      async_cp16(gB0 + go, Bs[cur ^ 1] + lo0);
      async_cp16(gB1 + go, Bs[cur ^ 1] + lo1);
    }

    short8 af[4], bfr[4];
#pragma unroll
    for (int mi = 0; mi < 4; mi++) {
      int ar = wr * 64 + mi * 16 + lm;
      af[mi] = *(const short8*)(As[cur] + ar * 32 + swz * 8);
    }
#pragma unroll
    for (int ni = 0; ni < 4; ni++) {
      int bc = wc * 64 + ni * 16 + lm;
      bfr[ni] = *(const short8*)(Bs[cur] + bc * 32 + swz * 8);
    }
#pragma unroll
    for (int mi = 0; mi < 4; mi++)
#pragma unroll
      for (int ni = 0; ni < 4; ni++)
        acc[mi][ni] = __builtin_amdgcn_mfma_f32_16x16x32_bf16(
            af[mi], bfr[ni], acc[mi][ni], 0, 0, 0);
  }

  // Epilogue. C/D layout: col=lane&15, row=(lane>>4)*4+reg (m89-verified).
  float rsum[4][4];  // per (mi, rr): sum over ni, lm-reduced later
  float csum[4];     // per ni: sum over mi, rr, q-reduced later
#pragma unroll
  for (int mi = 0; mi < 4; mi++)
#pragma unroll
    for (int rr = 0; rr < 4; rr++) rsum[mi][rr] = 0.f;
#pragma unroll
  for (int ni = 0; ni < 4; ni++) csum[ni] = 0.f;

#pragma unroll
  for (int mi = 0; mi < 4; mi++) {
#pragma unroll
    for (int ni = 0; ni < 4; ni++) {
#pragma unroll
      for (int rr = 0; rr < 4; rr++) {
        int R = ri * 128 + wr * 64 + mi * 16 + q * 4 + rr;
        int Cg = cj * 128 + wc * 64 + ni * 16 + lm;
        float e = (R != Cg) ? __expf(acc[mi][ni][rr] - EXP_OFF) : 0.f;
        rsum[mi][rr] += e;
        csum[ni] += e;
      }
    }
  }

  // Row-sums: reduce across the 16 lm lanes (q preserved).
#pragma unroll
  for (int mi = 0; mi < 4; mi++) {
#pragma unroll
    for (int rr = 0; rr < 4; rr++) {
      float s = rsum[mi][rr];
      s += __shfl_xor(s, 1);
      s += __shfl_xor(s, 2);
      s += __shfl_xor(s, 4);
      s += __shfl_xor(s, 8);
      if (lm == 0) {
        int R = ri * 128 + wr * 64 + mi * 16 + q * 4 + rr;
        part[((size_t)(b * 4096 + R)) * 64 + cj * 2 + wc] = s;
      }
    }
  }

  // Col-sums (off-diagonal tiles only): reduce across the 4 q lanes.
  if (ri != cj) {
#pragma unroll
    for (int ni = 0; ni < 4; ni++) {
      float s = csum[ni];
      s += __shfl_xor(s, 16);
      s += __shfl_xor(s, 32);
      if (q == 0) {
        int Cg = cj * 128 + wc * 64 + ni * 16 + lm;
        part[((size_t)(b * 4096 + Cg)) * 64 + ri * 2 + wr] = s;
      }
    }
  }
}

// lse_temp[row] = 80 + log(sum of 64 partials). One thread per row.
__global__ __launch_bounds__(256) void merge_row_kernel(
    const float* __restrict__ part, float* __restrict__ lse_temp) {
  int row = blockIdx.x * 256 + threadIdx.x;  // 0..16383
  const float4* p = (const float4*)(part + (size_t)row * 64);
  float s = 0.f;
#pragma unroll
  for (int i = 0; i < 16; i++) {
    float4 v = p[i];
    s += v.x + v.y + v.z + v.w;
  }
  lse_temp[row] = EXP_OFF + __logf(s);
}

// ---------------------------------------------------------------------------
// Fused combine+topk (block 0) and cumsum phase A (blocks 1..512).
// Block 0: 7-round top-k over 2048 combined scores (latency-bound, 1 block).
// Blocks 1..512: per-32-row group sums of V into psum[bh][g][64] (overlaid
// on dead `part`) -- disjoint data from block 0, overlaps its latency.
// ---------------------------------------------------------------------------
__global__ __launch_bounds__(256) void combine_psum_kernel(
    const float* __restrict__ lse_inst, const float* __restrict__ lse_temp,
    const float* __restrict__ posdot, int* __restrict__ index_out,
    const float* __restrict__ V, float* __restrict__ psum) {
  if (blockIdx.x > 0) {
    // ---------------- cumsum phase A (was cumsum_psum_kernel) -------------
    int gb = (blockIdx.x - 1) * 4 + (threadIdx.x >> 6);  // 0..2047
    int bh = gb >> 6, g = gb & 63;
    int h = bh & 7, b = bh >> 3;
    int lane = threadIdx.x & 63;
    int ro = lane >> 4, e4 = (lane & 15) * 4;
    const float* base =
        V + (size_t)(b * 2048 + g * 32 + ro) * 512 + h * 64 + e4;
    float sx = 0.f, sy = 0.f, sz = 0.f, sw = 0.f;
#pragma unroll
    for (int k = 0; k < 8; k++) {
      float4 v = *(const float4*)(base + (size_t)(k * 4) * 512);
      sx += v.x; sy += v.y; sz += v.z; sw += v.w;
    }
    sx += __shfl_xor(sx, 16); sy += __shfl_xor(sy, 16);
    sz += __shfl_xor(sz, 16); sw += __shfl_xor(sw, 16);
    sx += __shfl_xor(sx, 32); sy += __shfl_xor(sy, 32);
    sz += __shfl_xor(sz, 32); sw += __shfl_xor(sw, 32);
    if (ro == 0) {
      float4 o = {sx, sy, sz, sw};
      *(float4*)(psum + ((size_t)bh * 64 + g) * 64 + e4) = o;
    }
    return;
  }

  // ---------------- combine + top-7 (was combine_topk_kernel) -------------
  __shared__ float wmax[4];
  __shared__ int widx[4];
  int tid = threadIdx.x;
  int base = tid * 8;
  float v[8];
#pragma unroll
  for (int r = 0; r < 8; r++) {
    int t = base + r;
    float sum = 0.f;
#pragma unroll
    for (int b = 0; b < 4; b++) {
      sum += 0.25f * (lse_inst[t * 8 + b] + lse_inst[t * 8 + 4 + b] +
                      lse_temp[b * 4096 + t] + lse_temp[b * 4096 + 2048 + t]) -
             posdot[b * 2048 + t];
    }
    v[r] = sum * 0.25f;
  }
  int lane = tid & 63, w = tid >> 6;
  for (int k = 0; k < 7; k++) {
    float bv = v[0];
    int bi = base;
#pragma unroll
    for (int r = 1; r < 8; r++)
      if (v[r] > bv) { bv = v[r]; bi = base + r; }
#pragma unroll
    for (int d = 1; d < 64; d <<= 1) {
      float ov = __shfl_xor(bv, d);
      int oi = __shfl_xor(bi, d);
      if (ov > bv || (ov == bv && oi < bi)) { bv = ov; bi = oi; }
    }
    if (lane == 0) { wmax[w] = bv; widx[w] = bi; }
    __syncthreads();
    float BV = wmax[0];
    int BI = widx[0];
#pragma unroll
    for (int ww = 1; ww < 4; ww++)
      if (wmax[ww] > BV || (wmax[ww] == BV && widx[ww] < BI)) {
        BV = wmax[ww];
        BI = widx[ww];
      }
    if (tid == 0) index_out[k] = BI;
    if (BI >= base && BI < base + 8) v[BI - base] = -INFINITY;
    __syncthreads();
  }
}

// ---------------------------------------------------------------------------
// Cumsum phase B: scan + write. grid = 32 bh * 16 chunks = 512 blocks.
// ---------------------------------------------------------------------------
__global__ __launch_bounds__(256) void cumsum_write_kernel(
    const float* __restrict__ V, const float* __restrict__ psum,
    const int* __restrict__ index, float* __restrict__ out) {
  int blk = blockIdx.x;             // 0..511
  int bh = blk >> 4, chunk = blk & 15;
  int h = bh & 7, b = bh >> 3;
  int tid = threadIdx.x;
  int e = tid & 63, sub = tid >> 6;
  int g = chunk * 4 + sub;          // 0..63

  const float* ps = psum + (size_t)bh * 64 * 64;
  float run = 0.f;
  for (int gg = 0; gg < g; ++gg) run += ps[gg * 64 + e];

  int idx[7];
#pragma unroll
  for (int k = 0; k < 7; k++) idx[k] = index[k];

  const float* Vbase = V + (size_t)(b * 2048) * 512 + h * 64 + e;
  float* obase = out + (size_t)bh * 2048 * 64 + e;

  int l0 = g * 32;
#pragma unroll 4
  for (int l = l0; l < l0 + 32; ++l) {
    run += Vbase[(size_t)l * 512];
    float o = run;
    bool special = false;
#pragma unroll
    for (int k = 0; k < 7; k++) special = special || (idx[k] == l);
    if (special) o = run / (float)(l + 1);
    obase[(size_t)l * 64] = o;
  }
}

extern "C" void kernel_launch(void* const* d_in, const int* in_sizes, int n_in,
                              void* d_out, int out_size, void* d_ws, size_t ws_size,
                              hipStream_t stream) {
  const float* Q = (const float*)d_in[0];  // (4,2048,512)
  const float* K = (const float*)d_in[1];
  const float* V = (const float*)d_in[2];
  float* out = (float*)d_out;              // (4,8,2048,64)

  // Workspace layout:
  unsigned short* Z = (unsigned short*)d_ws;        // 4*4096*512 bf16 = 16.8 MB
  float* base = (float*)d_ws + 4 * 4096 * 512 / 2;  // after Z
  float* part = base;                               // 4*4096*64 = 1M floats
  float* lse_t = base + 4 * 4096 * 64;              // 16384
  float* lse_i = lse_t + 16384;                     // 16384
  float* posd = lse_i + 16384;                      // 8192
  int* idx = (int*)(posd + 8192);                   // 8
  float* psum = part;  // 32*64*64 floats = 512 KB, reuses dead `part`

  convert_bf16_kernel<<<4096, 256, 0, stream>>>(Q, K, Z);
  // Blocks 0..2111: gram tiles; 2112..2367: fused instance path.
  temporal_gemm_kernel<<<2368, 256, 0, stream>>>(Z, part, lse_i, posd);
  merge_row_kernel<<<64, 256, 0, stream>>>(part, lse_t);
  // Block 0: combine+top7; blocks 1..512: cumsum psum (part is dead after
  // merge_row; safe to overlay).
  combine_psum_kernel<<<513, 256, 0, stream>>>(lse_i, lse_t, posd, idx, V,
                                               psum);
  cumsum_write_kernel<<<512, 256, 0, stream>>>(V, psum, idx, out);
}

// Round 5
// 188.054 us; speedup vs baseline: 1.1039x; 1.0442x over previous
//
#include <hip/hip_runtime.h>
#include <math.h>

// Problem constants: B=4, L=T=2048, H=8, E=64, C=H*E=512, top_k=7
// Output = cumsum(V) with top-7 rows (by corrmean) replaced by running mean.
// Only the top-7 index SET of corrmean affects the output -> grams in bf16
// MFMA. Temporal LSE uses fixed exp-offset 80; sum-only partials.
// R6: symmetric gram -> upper-triangle tiles only (528/1024 per batch).
// R9: cumsum split into full-GPU psum+write phases.
// R10/R11: 256x256 deep-pipeline attempts REGRESSED (72.6/66.8 us vs R7's
//     59.2). K=512 (16 K-steps) is out of the m201 template's regime.
// R12: __launch_bounds__(256,4) clamp -> VGPR 64 -> MAIN-LOOP SPILLS
//     (WRITE_SIZE 9->45 MB, 71.2 us). Occupancy push refuted: 64 AGPR acc
//     is incompressible. BUT fusions saved ~9 us of makespan.
// R13 (this round): R7 gram verbatim (launch_bounds(256,3), VGPR 80,
//     no spills, 59.2 us) + keep R12's two fusions (instance in temporal
//     tail blocks >= 2112; cumsum-psum in combine launch blocks >= 1).

typedef __attribute__((ext_vector_type(8))) short short8;
typedef __attribute__((ext_vector_type(8))) unsigned short ushort8;
typedef __attribute__((ext_vector_type(4))) float f32x4;

typedef const __attribute__((address_space(1))) void* gas_ptr;
typedef __attribute__((address_space(3))) void* las_ptr;

#define EXP_OFF 80.0f

__device__ __forceinline__ void async_cp16(const void* g, void* l) {
  // LDS dest is wave-uniform base; HW adds lane*16 (m104/m108).
  __builtin_amdgcn_global_load_lds((gas_ptr)g, (las_ptr)l, 16, 0, 0);
}

__device__ __forceinline__ unsigned short f2bf(float x) {
  union { float f; unsigned int u; } v; v.f = x;
  unsigned int r = v.u + 0x7FFFu + ((v.u >> 16) & 1u);  // RNE
  return (unsigned short)(r >> 16);
}

// ---------------------------------------------------------------------------
// Convert Q,K fp32 -> Z bf16 [4][4096][512] (rows 0..2047 = Q, 2048.. = K)
// ---------------------------------------------------------------------------
__global__ __launch_bounds__(256) void convert_bf16_kernel(
    const float* __restrict__ Q, const float* __restrict__ K,
    unsigned short* __restrict__ Z) {
  int tid = blockIdx.x * 256 + threadIdx.x;  // 0..1048575
  int row = tid >> 6;                        // b*4096 + i
  int c0 = (tid & 63) * 8;
  int b = row >> 12, i = row & 4095;
  const float* src = (i < 2048)
      ? Q + ((size_t)(b * 2048 + i) * 512 + c0)
      : K + ((size_t)(b * 2048 + (i - 2048)) * 512 + c0);
  float4 v0 = ((const float4*)src)[0];
  float4 v1 = ((const float4*)src)[1];
  ushort8 o;
  o[0] = f2bf(v0.x); o[1] = f2bf(v0.y); o[2] = f2bf(v0.z); o[3] = f2bf(v0.w);
  o[4] = f2bf(v1.x); o[5] = f2bf(v1.y); o[6] = f2bf(v1.z); o[7] = f2bf(v1.w);
  *(ushort8*)(Z + (size_t)row * 512 + c0) = o;
}

// ---------------------------------------------------------------------------
// Temporal gram (blocks 0..2111): upper-triangle 128x128 tiles (ri<=cj over
// 32x32 tile grid), 16x16x32 bf16 MFMA, BK=32, double-buffered LDS (one
// barrier per kc), XOR-swizzled staging (bank-conflict 0 verified).
// XCD-pair swizzle: b=(id&7)>>1. Epilogue: e=exp(v-80) feeds row-sums
// (slot cj*2+wc) and, off-diagonal, col-sums (slot ri*2+wr) -- slot union
// [0,64) complete per row, no zero-fill needed.
// Blocks 2112..2367: fused instance-LSE path (reads Z only; writes
// lse_inst/posdot -- disjoint from part).
// __launch_bounds__(256,3) = R7's verified regime: VGPR 80, zero spills.
// (256,4) was tried in R12 -> VGPR 64 -> main-loop spills, +36 MB scratch.
// ---------------------------------------------------------------------------
__global__ __launch_bounds__(256, 3) void temporal_gemm_kernel(
    const unsigned short* __restrict__ Z, float* __restrict__ part,
    float* __restrict__ lse_inst /* [2048][8] */,
    float* __restrict__ posdot /* [4][2048] */) {
  __shared__ __align__(16) unsigned short As[2][128 * 32];  // 2 x 8 KB
  __shared__ __align__(16) unsigned short Bs[2][128 * 32];  // 2 x 8 KB

  if (blockIdx.x >= 2112) {
    // ---------------- instance path (was instance_kernel) ----------------
    int wave = ((blockIdx.x - 2112) * 256 + threadIdx.x) >> 6;  // 0..1023
    int t0 = wave * 2;
    int lane = threadIdx.x & 63;
    int lm = lane & 15, q = lane >> 4;
    int tt = (lm < 8) ? t0 : t0 + 1;
    int v = lm & 7;
    size_t zrow = (v < 4) ? ((size_t)v * 4096 + tt)
                          : ((size_t)(v - 4) * 4096 + 2048 + tt);
    const unsigned short* g = Z + zrow * 512 + q * 8;

    f32x4 acc0 = (f32x4)(0.f), acc1 = (f32x4)(0.f);
#pragma unroll
    for (int kc = 0; kc < 16; kc += 2) {
      short8 a0 = *(const short8*)(g + kc * 32);
      short8 a1 = *(const short8*)(g + kc * 32 + 32);
      acc0 = __builtin_amdgcn_mfma_f32_16x16x32_bf16(a0, a0, acc0, 0, 0, 0);
      acc1 = __builtin_amdgcn_mfma_f32_16x16x32_bf16(a1, a1, acc1, 0, 0, 0);
    }
    f32x4 acc = acc0 + acc1;

#pragma unroll
    for (int rr = 0; rr < 4; rr++) {
      int i = q * 4 + rr;                      // row 0..15
      float val = acc[rr];
      bool samehalf = ((i < 8) == (lm < 8));
      int t = (i < 8) ? t0 : t0 + 1;
      int iv = i & 7;
      if (samehalf && iv < 4 && (lm & 7) == iv + 4)
        posdot[iv * 2048 + t] = val;
      float dd = (samehalf && lm != i) ? val : -INFINITY;
      float mt = dd;
      mt = fmaxf(mt, __shfl_xor(mt, 1));
      mt = fmaxf(mt, __shfl_xor(mt, 2));
      mt = fmaxf(mt, __shfl_xor(mt, 4));
      float e = __expf(dd - mt);
      e += __shfl_xor(e, 1);
      e += __shfl_xor(e, 2);
      e += __shfl_xor(e, 4);
      if ((lm & 7) == 0 && samehalf) lse_inst[t * 8 + iv] = mt + __logf(e);
    }
    return;
  }

  // ------------------------- gram path (R7 verbatim) ----------------------
  int id = blockIdx.x;                  // 0..2111
  int x = id & 7;
  int b = x >> 1;                       // XCD-pair lock per batch
  int t = (id >> 3) * 2 + (x & 1);      // 0..527
  // invert t = cj*(cj+1)/2 + ri, ri<=cj
  int cj = (int)((sqrtf(8.0f * (float)t + 1.0f) - 1.0f) * 0.5f);
  while ((cj + 1) * (cj + 2) / 2 <= t) cj++;
  while (cj * (cj + 1) / 2 > t) cj--;
  int ri = t - cj * (cj + 1) / 2;
  const unsigned short* Zb = Z + (size_t)b * 4096 * 512;

  int tid = threadIdx.x;
  int w = tid >> 6, lane = tid & 63;
  int wr = w >> 1, wc = w & 1;
  int lm = lane & 15, q = lane >> 4;
  int swz = q ^ ((lm >> 1) & 3);  // frag-read physical chunk

  // Staging: slot row = w*16 + (lane>>2), physical chunk lane&3 holds
  // logical chunk kq = (lane&3)^((lane>>3)&3)
  int srow = lane >> 2;
  int kq = (lane & 3) ^ ((lane >> 3) & 3);
  int rl0 = w * 16 + srow;
  int rl1 = 64 + rl0;
  const unsigned short* gA0 = Zb + (size_t)(ri * 128 + rl0) * 512 + kq * 8;
  const unsigned short* gA1 = Zb + (size_t)(ri * 128 + rl1) * 512 + kq * 8;
  const unsigned short* gB0 = Zb + (size_t)(cj * 128 + rl0) * 512 + kq * 8;
  const unsigned short* gB1 = Zb + (size_t)(cj * 128 + rl1) * 512 + kq * 8;
  int lo0 = (w * 16) * 32;        // wave-uniform base offsets
  int lo1 = (64 + w * 16) * 32;

  f32x4 acc[4][4];
#pragma unroll
  for (int mi = 0; mi < 4; mi++)
#pragma unroll
    for (int ni = 0; ni < 4; ni++) acc[mi][ni] = (f32x4)(0.f);

  // Prologue: stage kc=0 into buffer 0.
  async_cp16(gA0, As[0] + lo0);
  async_cp16(gA1, As[0] + lo1);
  async_cp16(gB0, Bs[0] + lo0);
  async_cp16(gB1, Bs[0] + lo1);

  for (int kc = 0; kc < 16; ++kc) {
    int cur = kc & 1;
    __syncthreads();  // drains stage(kc) — issued one compute phase ago

    if (kc < 15) {
      int go = (kc + 1) * 32;
      async_cp16(gA0 + go, As[cur ^ 1] + lo0);
      async_cp16(gA1 + go, As[cur ^ 1] + lo1);
      async_cp16(gB0 + go, Bs[cur ^ 1] + lo0);
      async_cp16(gB1 + go, Bs[cur ^ 1] + lo1);
    }

    short8 af[4], bfr[4];
#pragma unroll
    for (int mi = 0; mi < 4; mi++) {
      int ar = wr * 64 + mi * 16 + lm;
      af[mi] = *(const short8*)(As[cur] + ar * 32 + swz * 8);
    }
#pragma unroll
    for (int ni = 0; ni < 4; ni++) {
      int bc = wc * 64 + ni * 16 + lm;
      bfr[ni] = *(const short8*)(Bs[cur] + bc * 32 + swz * 8);
    }
#pragma unroll
    for (int mi = 0; mi < 4; mi++)
#pragma unroll
      for (int ni = 0; ni < 4; ni++)
        acc[mi][ni] = __builtin_amdgcn_mfma_f32_16x16x32_bf16(
            af[mi], bfr[ni], acc[mi][ni], 0, 0, 0);
  }

  // Epilogue. C/D layout: col=lane&15, row=(lane>>4)*4+reg (m89-verified).
  float rsum[4][4];  // per (mi, rr): sum over ni, lm-reduced later
  float csum[4];     // per ni: sum over mi, rr, q-reduced later
#pragma unroll
  for (int mi = 0; mi < 4; mi++)
#pragma unroll
    for (int rr = 0; rr < 4; rr++) rsum[mi][rr] = 0.f;
#pragma unroll
  for (int ni = 0; ni < 4; ni++) csum[ni] = 0.f;

#pragma unroll
  for (int mi = 0; mi < 4; mi++) {
#pragma unroll
    for (int ni = 0; ni < 4; ni++) {
#pragma unroll
      for (int rr = 0; rr < 4; rr++) {
        int R = ri * 128 + wr * 64 + mi * 16 + q * 4 + rr;
        int Cg = cj * 128 + wc * 64 + ni * 16 + lm;
        float e = (R != Cg) ? __expf(acc[mi][ni][rr] - EXP_OFF) : 0.f;
        rsum[mi][rr] += e;
        csum[ni] += e;
      }
    }
  }

  // Row-sums: reduce across the 16 lm lanes (q preserved).
#pragma unroll
  for (int mi = 0; mi < 4; mi++) {
#pragma unroll
    for (int rr = 0; rr < 4; rr++) {
      float s = rsum[mi][rr];
      s += __shfl_xor(s, 1);
      s += __shfl_xor(s, 2);
      s += __shfl_xor(s, 4);
      s += __shfl_xor(s, 8);
      if (lm == 0) {
        int R = ri * 128 + wr * 64 + mi * 16 + q * 4 + rr;
        part[((size_t)(b * 4096 + R)) * 64 + cj * 2 + wc] = s;
      }
    }
  }

  // Col-sums (off-diagonal tiles only): reduce across the 4 q lanes.
  if (ri != cj) {
#pragma unroll
    for (int ni = 0; ni < 4; ni++) {
      float s = csum[ni];
      s += __shfl_xor(s, 16);
      s += __shfl_xor(s, 32);
      if (q == 0) {
        int Cg = cj * 128 + wc * 64 + ni * 16 + lm;
        part[((size_t)(b * 4096 + Cg)) * 64 + ri * 2 + wr] = s;
      }
    }
  }
}

// lse_temp[row] = 80 + log(sum of 64 partials). One thread per row.
__global__ __launch_bounds__(256) void merge_row_kernel(
    const float* __restrict__ part, float* __restrict__ lse_temp) {
  int row = blockIdx.x * 256 + threadIdx.x;  // 0..16383
  const float4* p = (const float4*)(part + (size_t)row * 64);
  float s = 0.f;
#pragma unroll
  for (int i = 0; i < 16; i++) {
    float4 v = p[i];
    s += v.x + v.y + v.z + v.w;
  }
  lse_temp[row] = EXP_OFF + __logf(s);
}

// ---------------------------------------------------------------------------
// Fused combine+topk (block 0) and cumsum phase A (blocks 1..512).
// Block 0: 7-round top-k over 2048 combined scores (latency-bound, 1 block).
// Blocks 1..512: per-32-row group sums of V into psum[bh][g][64] (overlaid
// on dead `part`) -- disjoint data from block 0, overlaps its latency.
// ---------------------------------------------------------------------------
__global__ __launch_bounds__(256) void combine_psum_kernel(
    const float* __restrict__ lse_inst, const float* __restrict__ lse_temp,
    const float* __restrict__ posdot, int* __restrict__ index_out,
    const float* __restrict__ V, float* __restrict__ psum) {
  if (blockIdx.x > 0) {
    // ---------------- cumsum phase A (was cumsum_psum_kernel) -------------
    int gb = (blockIdx.x - 1) * 4 + (threadIdx.x >> 6);  // 0..2047
    int bh = gb >> 6, g = gb & 63;
    int h = bh & 7, b = bh >> 3;
    int lane = threadIdx.x & 63;
    int ro = lane >> 4, e4 = (lane & 15) * 4;
    const float* base =
        V + (size_t)(b * 2048 + g * 32 + ro) * 512 + h * 64 + e4;
    float sx = 0.f, sy = 0.f, sz = 0.f, sw = 0.f;
#pragma unroll
    for (int k = 0; k < 8; k++) {
      float4 v = *(const float4*)(base + (size_t)(k * 4) * 512);
      sx += v.x; sy += v.y; sz += v.z; sw += v.w;
    }
    sx += __shfl_xor(sx, 16); sy += __shfl_xor(sy, 16);
    sz += __shfl_xor(sz, 16); sw += __shfl_xor(sw, 16);
    sx += __shfl_xor(sx, 32); sy += __shfl_xor(sy, 32);
    sz += __shfl_xor(sz, 32); sw += __shfl_xor(sw, 32);
    if (ro == 0) {
      float4 o = {sx, sy, sz, sw};
      *(float4*)(psum + ((size_t)bh * 64 + g) * 64 + e4) = o;
    }
    return;
  }

  // ---------------- combine + top-7 (was combine_topk_kernel) -------------
  __shared__ float wmax[4];
  __shared__ int widx[4];
  int tid = threadIdx.x;
  int base = tid * 8;
  float v[8];
#pragma unroll
  for (int r = 0; r < 8; r++) {
    int t = base + r;
    float sum = 0.f;
#pragma unroll
    for (int b = 0; b < 4; b++) {
      sum += 0.25f * (lse_inst[t * 8 + b] + lse_inst[t * 8 + 4 + b] +
                      lse_temp[b * 4096 + t] + lse_temp[b * 4096 + 2048 + t]) -
             posdot[b * 2048 + t];
    }
    v[r] = sum * 0.25f;
  }
  int lane = tid & 63, w = tid >> 6;
  for (int k = 0; k < 7; k++) {
    float bv = v[0];
    int bi = base;
#pragma unroll
    for (int r = 1; r < 8; r++)
      if (v[r] > bv) { bv = v[r]; bi = base + r; }
#pragma unroll
    for (int d = 1; d < 64; d <<= 1) {
      float ov = __shfl_xor(bv, d);
      int oi = __shfl_xor(bi, d);
      if (ov > bv || (ov == bv && oi < bi)) { bv = ov; bi = oi; }
    }
    if (lane == 0) { wmax[w] = bv; widx[w] = bi; }
    __syncthreads();
    float BV = wmax[0];
    int BI = widx[0];
#pragma unroll
    for (int ww = 1; ww < 4; ww++)
      if (wmax[ww] > BV || (wmax[ww] == BV && widx[ww] < BI)) {
        BV = wmax[ww];
        BI = widx[ww];
      }
    if (tid == 0) index_out[k] = BI;
    if (BI >= base && BI < base + 8) v[BI - base] = -INFINITY;
    __syncthreads();
  }
}

// ---------------------------------------------------------------------------
// Cumsum phase B: scan + write. grid = 32 bh * 16 chunks = 512 blocks.
// ---------------------------------------------------------------------------
__global__ __launch_bounds__(256) void cumsum_write_kernel(
    const float* __restrict__ V, const float* __restrict__ psum,
    const int* __restrict__ index, float* __restrict__ out) {
  int blk = blockIdx.x;             // 0..511
  int bh = blk >> 4, chunk = blk & 15;
  int h = bh & 7, b = bh >> 3;
  int tid = threadIdx.x;
  int e = tid & 63, sub = tid >> 6;
  int g = chunk * 4 + sub;          // 0..63

  const float* ps = psum + (size_t)bh * 64 * 64;
  float run = 0.f;
  for (int gg = 0; gg < g; ++gg) run += ps[gg * 64 + e];

  int idx[7];
#pragma unroll
  for (int k = 0; k < 7; k++) idx[k] = index[k];

  const float* Vbase = V + (size_t)(b * 2048) * 512 + h * 64 + e;
  float* obase = out + (size_t)bh * 2048 * 64 + e;

  int l0 = g * 32;
#pragma unroll 4
  for (int l = l0; l < l0 + 32; ++l) {
    run += Vbase[(size_t)l * 512];
    float o = run;
    bool special = false;
#pragma unroll
    for (int k = 0; k < 7; k++) special = special || (idx[k] == l);
    if (special) o = run / (float)(l + 1);
    obase[(size_t)l * 64] = o;
  }
}

extern "C" void kernel_launch(void* const* d_in, const int* in_sizes, int n_in,
                              void* d_out, int out_size, void* d_ws, size_t ws_size,
                              hipStream_t stream) {
  const float* Q = (const float*)d_in[0];  // (4,2048,512)
  const float* K = (const float*)d_in[1];
  const float* V = (const float*)d_in[2];
  float* out = (float*)d_out;              // (4,8,2048,64)

  // Workspace layout:
  unsigned short* Z = (unsigned short*)d_ws;        // 4*4096*512 bf16 = 16.8 MB
  float* base = (float*)d_ws + 4 * 4096 * 512 / 2;  // after Z
  float* part = base;                               // 4*4096*64 = 1M floats
  float* lse_t = base + 4 * 4096 * 64;              // 16384
  float* lse_i = lse_t + 16384;                     // 16384
  float* posd = lse_i + 16384;                      // 8192
  int* idx = (int*)(posd + 8192);                   // 8
  float* psum = part;  // 32*64*64 floats = 512 KB, reuses dead `part`

  convert_bf16_kernel<<<4096, 256, 0, stream>>>(Q, K, Z);
  // Blocks 0..2111: gram tiles; 2112..2367: fused instance path.
  temporal_gemm_kernel<<<2368, 256, 0, stream>>>(Z, part, lse_i, posd);
  merge_row_kernel<<<64, 256, 0, stream>>>(part, lse_t);
  // Block 0: combine+top7; blocks 1..512: cumsum psum (part is dead after
  // merge_row; safe to overlay).
  combine_psum_kernel<<<513, 256, 0, stream>>>(lse_i, lse_t, posd, idx, V,
                                               psum);
  cumsum_write_kernel<<<512, 256, 0, stream>>>(V, psum, idx, out);
}

// Round 6
// 182.791 us; speedup vs baseline: 1.1357x; 1.0288x over previous
//
#include <hip/hip_runtime.h>
#include <math.h>

// Problem constants: B=4, L=T=2048, H=8, E=64, C=H*E=512, top_k=7
// Output = cumsum(V) with top-7 rows (by corrmean) replaced by running mean.
// Only the top-7 index SET of corrmean affects the output -> grams in bf16
// MFMA. Temporal LSE uses fixed exp-offset 80; sum-only partials.
// R6: symmetric gram -> upper-triangle tiles only (528/1024 per batch).
// R9: cumsum split into full-GPU psum+write phases.
// R10/R11: 256x256 deep-pipeline attempts REGRESSED (72.6/66.8 us): geometry
//     change (128KB LDS -> 1 block/CU) killed inter-block overlap.
// R12: (256,4) clamp -> VGPR 64 -> main-loop spills. Fusions kept (~9 us).
// R13: R7 gram + fusions = 188.0 us total, temporal 59.8, VGPR 80. BEST.
// R14 (this round): ONE axis on top of R13 — replace the per-kc
//     __syncthreads (vmcnt(0) drain = the m97 stall) with a 3-slot LDS ring
//     + counted s_waitcnt vmcnt(4) + raw s_barrier, still ONE barrier/kc.
//     Stage(kc+2) lands in the slot read at kc-1 (consumed before any wave
//     reaches the kc barrier: frag regs force lgkmcnt before MFMA issue).
//     LDS 48 KB -> still 3 blocks/CU; geometry/swizzle/epilogue unchanged.

typedef __attribute__((ext_vector_type(8))) short short8;
typedef __attribute__((ext_vector_type(8))) unsigned short ushort8;
typedef __attribute__((ext_vector_type(4))) float f32x4;

typedef const __attribute__((address_space(1))) void* gas_ptr;
typedef __attribute__((address_space(3))) void* las_ptr;

#define EXP_OFF 80.0f

__device__ __forceinline__ void async_cp16(const void* g, void* l) {
  // LDS dest is wave-uniform base; HW adds lane*16 (m104/m108).
  __builtin_amdgcn_global_load_lds((gas_ptr)g, (las_ptr)l, 16, 0, 0);
}

__device__ __forceinline__ unsigned short f2bf(float x) {
  union { float f; unsigned int u; } v; v.f = x;
  unsigned int r = v.u + 0x7FFFu + ((v.u >> 16) & 1u);  // RNE
  return (unsigned short)(r >> 16);
}

// ---------------------------------------------------------------------------
// Convert Q,K fp32 -> Z bf16 [4][4096][512] (rows 0..2047 = Q, 2048.. = K)
// ---------------------------------------------------------------------------
__global__ __launch_bounds__(256) void convert_bf16_kernel(
    const float* __restrict__ Q, const float* __restrict__ K,
    unsigned short* __restrict__ Z) {
  int tid = blockIdx.x * 256 + threadIdx.x;  // 0..1048575
  int row = tid >> 6;                        // b*4096 + i
  int c0 = (tid & 63) * 8;
  int b = row >> 12, i = row & 4095;
  const float* src = (i < 2048)
      ? Q + ((size_t)(b * 2048 + i) * 512 + c0)
      : K + ((size_t)(b * 2048 + (i - 2048)) * 512 + c0);
  float4 v0 = ((const float4*)src)[0];
  float4 v1 = ((const float4*)src)[1];
  ushort8 o;
  o[0] = f2bf(v0.x); o[1] = f2bf(v0.y); o[2] = f2bf(v0.z); o[3] = f2bf(v0.w);
  o[4] = f2bf(v1.x); o[5] = f2bf(v1.y); o[6] = f2bf(v1.z); o[7] = f2bf(v1.w);
  *(ushort8*)(Z + (size_t)row * 512 + c0) = o;
}

// ---------------------------------------------------------------------------
// Temporal gram (blocks 0..2111): upper-triangle 128x128 tiles (ri<=cj over
// 32x32 tile grid), 16x16x32 bf16 MFMA, BK=32, 3-slot LDS ring, counted
// vmcnt(4) + one raw s_barrier per kc (never a full drain in-loop).
// XOR-swizzled staging (bank-conflict 0 verified). XCD-pair swizzle:
// b=(id&7)>>1. Epilogue: e=exp(v-80) feeds row-sums (slot cj*2+wc) and,
// off-diagonal, col-sums (slot ri*2+wr) -- slot union [0,64) complete.
// Blocks 2112..2367: fused instance-LSE path (reads Z only).
// __launch_bounds__(256,3): VGPR-80 regime, zero spills (R12 lesson).
// ---------------------------------------------------------------------------
__global__ __launch_bounds__(256, 3) void temporal_gemm_kernel(
    const unsigned short* __restrict__ Z, float* __restrict__ part,
    float* __restrict__ lse_inst /* [2048][8] */,
    float* __restrict__ posdot /* [4][2048] */) {
  __shared__ __align__(16) unsigned short As[3][128 * 32];  // 3 x 8 KB
  __shared__ __align__(16) unsigned short Bs[3][128 * 32];  // 3 x 8 KB

  if (blockIdx.x >= 2112) {
    // ---------------- instance path (was instance_kernel) ----------------
    int wave = ((blockIdx.x - 2112) * 256 + threadIdx.x) >> 6;  // 0..1023
    int t0 = wave * 2;
    int lane = threadIdx.x & 63;
    int lm = lane & 15, q = lane >> 4;
    int tt = (lm < 8) ? t0 : t0 + 1;
    int v = lm & 7;
    size_t zrow = (v < 4) ? ((size_t)v * 4096 + tt)
                          : ((size_t)(v - 4) * 4096 + 2048 + tt);
    const unsigned short* g = Z + zrow * 512 + q * 8;

    f32x4 acc0 = (f32x4)(0.f), acc1 = (f32x4)(0.f);
#pragma unroll
    for (int kc = 0; kc < 16; kc += 2) {
      short8 a0 = *(const short8*)(g + kc * 32);
      short8 a1 = *(const short8*)(g + kc * 32 + 32);
      acc0 = __builtin_amdgcn_mfma_f32_16x16x32_bf16(a0, a0, acc0, 0, 0, 0);
      acc1 = __builtin_amdgcn_mfma_f32_16x16x32_bf16(a1, a1, acc1, 0, 0, 0);
    }
    f32x4 acc = acc0 + acc1;

#pragma unroll
    for (int rr = 0; rr < 4; rr++) {
      int i = q * 4 + rr;                      // row 0..15
      float val = acc[rr];
      bool samehalf = ((i < 8) == (lm < 8));
      int t = (i < 8) ? t0 : t0 + 1;
      int iv = i & 7;
      if (samehalf && iv < 4 && (lm & 7) == iv + 4)
        posdot[iv * 2048 + t] = val;
      float dd = (samehalf && lm != i) ? val : -INFINITY;
      float mt = dd;
      mt = fmaxf(mt, __shfl_xor(mt, 1));
      mt = fmaxf(mt, __shfl_xor(mt, 2));
      mt = fmaxf(mt, __shfl_xor(mt, 4));
      float e = __expf(dd - mt);
      e += __shfl_xor(e, 1);
      e += __shfl_xor(e, 2);
      e += __shfl_xor(e, 4);
      if ((lm & 7) == 0 && samehalf) lse_inst[t * 8 + iv] = mt + __logf(e);
    }
    return;
  }

  // ------------------------- gram path ------------------------------------
  int id = blockIdx.x;                  // 0..2111
  int x = id & 7;
  int b = x >> 1;                       // XCD-pair lock per batch
  int t = (id >> 3) * 2 + (x & 1);      // 0..527
  // invert t = cj*(cj+1)/2 + ri, ri<=cj
  int cj = (int)((sqrtf(8.0f * (float)t + 1.0f) - 1.0f) * 0.5f);
  while ((cj + 1) * (cj + 2) / 2 <= t) cj++;
  while (cj * (cj + 1) / 2 > t) cj--;
  int ri = t - cj * (cj + 1) / 2;
  const unsigned short* Zb = Z + (size_t)b * 4096 * 512;

  int tid = threadIdx.x;
  int w = tid >> 6, lane = tid & 63;
  int wr = w >> 1, wc = w & 1;
  int lm = lane & 15, q = lane >> 4;
  int swz = q ^ ((lm >> 1) & 3);  // frag-read physical chunk

  // Staging: slot row = w*16 + (lane>>2), physical chunk lane&3 holds
  // logical chunk kq = (lane&3)^((lane>>3)&3)
  int srow = lane >> 2;
  int kq = (lane & 3) ^ ((lane >> 3) & 3);
  int rl0 = w * 16 + srow;
  int rl1 = 64 + rl0;
  const unsigned short* gA0 = Zb + (size_t)(ri * 128 + rl0) * 512 + kq * 8;
  const unsigned short* gA1 = Zb + (size_t)(ri * 128 + rl1) * 512 + kq * 8;
  const unsigned short* gB0 = Zb + (size_t)(cj * 128 + rl0) * 512 + kq * 8;
  const unsigned short* gB1 = Zb + (size_t)(cj * 128 + rl1) * 512 + kq * 8;
  int lo0 = (w * 16) * 32;        // wave-uniform base offsets
  int lo1 = (64 + w * 16) * 32;

  f32x4 acc[4][4];
#pragma unroll
  for (int mi = 0; mi < 4; mi++)
#pragma unroll
    for (int ni = 0; ni < 4; ni++) acc[mi][ni] = (f32x4)(0.f);

#define STAGE(kc_, sl_)                                  \
  do {                                                   \
    int go_ = (kc_) * 32;                                \
    async_cp16(gA0 + go_, As[sl_] + lo0);                \
    async_cp16(gA1 + go_, As[sl_] + lo1);                \
    async_cp16(gB0 + go_, Bs[sl_] + lo0);                \
    async_cp16(gB1 + go_, Bs[sl_] + lo1);                \
  } while (0)

  // Prologue: tiles 0,1 into slots 0,1 (8 loads outstanding per wave).
  STAGE(0, 0);
  STAGE(1, 1);

  int sl = 0;  // ring slot holding tile kc
  for (int kc = 0; kc < 16; ++kc) {
    // Wait for tile kc's 4 loads (oldest); keep newer tiles in flight.
    if (kc < 15)
      asm volatile("s_waitcnt vmcnt(4)" ::: "memory");
    else
      asm volatile("s_waitcnt vmcnt(0)" ::: "memory");
    // One barrier per kc: all waves have tile kc landed AND have consumed
    // their tile-(kc-1) ds_reads (frag regs force lgkmcnt before MFMA).
    asm volatile("s_barrier" ::: "memory");

    // Stage tile kc+2 into the slot read at kc-1 (now provably free).
    if (kc + 2 < 16) {
      int ss = sl + 2;
      if (ss >= 3) ss -= 3;
      STAGE(kc + 2, ss);
    }

    short8 af[4], bfr[4];
#pragma unroll
    for (int mi = 0; mi < 4; mi++) {
      int ar = wr * 64 + mi * 16 + lm;
      af[mi] = *(const short8*)(As[sl] + ar * 32 + swz * 8);
    }
#pragma unroll
    for (int ni = 0; ni < 4; ni++) {
      int bc = wc * 64 + ni * 16 + lm;
      bfr[ni] = *(const short8*)(Bs[sl] + bc * 32 + swz * 8);
    }
#pragma unroll
    for (int mi = 0; mi < 4; mi++)
#pragma unroll
      for (int ni = 0; ni < 4; ni++)
        acc[mi][ni] = __builtin_amdgcn_mfma_f32_16x16x32_bf16(
            af[mi], bfr[ni], acc[mi][ni], 0, 0, 0);

    sl = (sl + 1 == 3) ? 0 : sl + 1;
  }
#undef STAGE

  // Epilogue. C/D layout: col=lane&15, row=(lane>>4)*4+reg (m89-verified).
  float rsum[4][4];  // per (mi, rr): sum over ni, lm-reduced later
  float csum[4];     // per ni: sum over mi, rr, q-reduced later
#pragma unroll
  for (int mi = 0; mi < 4; mi++)
#pragma unroll
    for (int rr = 0; rr < 4; rr++) rsum[mi][rr] = 0.f;
#pragma unroll
  for (int ni = 0; ni < 4; ni++) csum[ni] = 0.f;

#pragma unroll
  for (int mi = 0; mi < 4; mi++) {
#pragma unroll
    for (int ni = 0; ni < 4; ni++) {
#pragma unroll
      for (int rr = 0; rr < 4; rr++) {
        int R = ri * 128 + wr * 64 + mi * 16 + q * 4 + rr;
        int Cg = cj * 128 + wc * 64 + ni * 16 + lm;
        float e = (R != Cg) ? __expf(acc[mi][ni][rr] - EXP_OFF) : 0.f;
        rsum[mi][rr] += e;
        csum[ni] += e;
      }
    }
  }

  // Row-sums: reduce across the 16 lm lanes (q preserved).
#pragma unroll
  for (int mi = 0; mi < 4; mi++) {
#pragma unroll
    for (int rr = 0; rr < 4; rr++) {
      float s = rsum[mi][rr];
      s += __shfl_xor(s, 1);
      s += __shfl_xor(s, 2);
      s += __shfl_xor(s, 4);
      s += __shfl_xor(s, 8);
      if (lm == 0) {
        int R = ri * 128 + wr * 64 + mi * 16 + q * 4 + rr;
        part[((size_t)(b * 4096 + R)) * 64 + cj * 2 + wc] = s;
      }
    }
  }

  // Col-sums (off-diagonal tiles only): reduce across the 4 q lanes.
  if (ri != cj) {
#pragma unroll
    for (int ni = 0; ni < 4; ni++) {
      float s = csum[ni];
      s += __shfl_xor(s, 16);
      s += __shfl_xor(s, 32);
      if (q == 0) {
        int Cg = cj * 128 + wc * 64 + ni * 16 + lm;
        part[((size_t)(b * 4096 + Cg)) * 64 + ri * 2 + wr] = s;
      }
    }
  }
}

// lse_temp[row] = 80 + log(sum of 64 partials). One thread per row.
__global__ __launch_bounds__(256) void merge_row_kernel(
    const float* __restrict__ part, float* __restrict__ lse_temp) {
  int row = blockIdx.x * 256 + threadIdx.x;  // 0..16383
  const float4* p = (const float4*)(part + (size_t)row * 64);
  float s = 0.f;
#pragma unroll
  for (int i = 0; i < 16; i++) {
    float4 v = p[i];
    s += v.x + v.y + v.z + v.w;
  }
  lse_temp[row] = EXP_OFF + __logf(s);
}

// ---------------------------------------------------------------------------
// Fused combine+topk (block 0) and cumsum phase A (blocks 1..512).
// Block 0: 7-round top-k over 2048 combined scores (latency-bound, 1 block).
// Blocks 1..512: per-32-row group sums of V into psum[bh][g][64] (overlaid
// on dead `part`) -- disjoint data from block 0, overlaps its latency.
// ---------------------------------------------------------------------------
__global__ __launch_bounds__(256) void combine_psum_kernel(
    const float* __restrict__ lse_inst, const float* __restrict__ lse_temp,
    const float* __restrict__ posdot, int* __restrict__ index_out,
    const float* __restrict__ V, float* __restrict__ psum) {
  if (blockIdx.x > 0) {
    // ---------------- cumsum phase A (was cumsum_psum_kernel) -------------
    int gb = (blockIdx.x - 1) * 4 + (threadIdx.x >> 6);  // 0..2047
    int bh = gb >> 6, g = gb & 63;
    int h = bh & 7, b = bh >> 3;
    int lane = threadIdx.x & 63;
    int ro = lane >> 4, e4 = (lane & 15) * 4;
    const float* base =
        V + (size_t)(b * 2048 + g * 32 + ro) * 512 + h * 64 + e4;
    float sx = 0.f, sy = 0.f, sz = 0.f, sw = 0.f;
#pragma unroll
    for (int k = 0; k < 8; k++) {
      float4 v = *(const float4*)(base + (size_t)(k * 4) * 512);
      sx += v.x; sy += v.y; sz += v.z; sw += v.w;
    }
    sx += __shfl_xor(sx, 16); sy += __shfl_xor(sy, 16);
    sz += __shfl_xor(sz, 16); sw += __shfl_xor(sw, 16);
    sx += __shfl_xor(sx, 32); sy += __shfl_xor(sy, 32);
    sz += __shfl_xor(sz, 32); sw += __shfl_xor(sw, 32);
    if (ro == 0) {
      float4 o = {sx, sy, sz, sw};
      *(float4*)(psum + ((size_t)bh * 64 + g) * 64 + e4) = o;
    }
    return;
  }

  // ---------------- combine + top-7 (was combine_topk_kernel) -------------
  __shared__ float wmax[4];
  __shared__ int widx[4];
  int tid = threadIdx.x;
  int base = tid * 8;
  float v[8];
#pragma unroll
  for (int r = 0; r < 8; r++) {
    int t = base + r;
    float sum = 0.f;
#pragma unroll
    for (int b = 0; b < 4; b++) {
      sum += 0.25f * (lse_inst[t * 8 + b] + lse_inst[t * 8 + 4 + b] +
                      lse_temp[b * 4096 + t] + lse_temp[b * 4096 + 2048 + t]) -
             posdot[b * 2048 + t];
    }
    v[r] = sum * 0.25f;
  }
  int lane = tid & 63, w = tid >> 6;
  for (int k = 0; k < 7; k++) {
    float bv = v[0];
    int bi = base;
#pragma unroll
    for (int r = 1; r < 8; r++)
      if (v[r] > bv) { bv = v[r]; bi = base + r; }
#pragma unroll
    for (int d = 1; d < 64; d <<= 1) {
      float ov = __shfl_xor(bv, d);
      int oi = __shfl_xor(bi, d);
      if (ov > bv || (ov == bv && oi < bi)) { bv = ov; bi = oi; }
    }
    if (lane == 0) { wmax[w] = bv; widx[w] = bi; }
    __syncthreads();
    float BV = wmax[0];
    int BI = widx[0];
#pragma unroll
    for (int ww = 1; ww < 4; ww++)
      if (wmax[ww] > BV || (wmax[ww] == BV && widx[ww] < BI)) {
        BV = wmax[ww];
        BI = widx[ww];
      }
    if (tid == 0) index_out[k] = BI;
    if (BI >= base && BI < base + 8) v[BI - base] = -INFINITY;
    __syncthreads();
  }
}

// ---------------------------------------------------------------------------
// Cumsum phase B: scan + write. grid = 32 bh * 16 chunks = 512 blocks.
// ---------------------------------------------------------------------------
__global__ __launch_bounds__(256) void cumsum_write_kernel(
    const float* __restrict__ V, const float* __restrict__ psum,
    const int* __restrict__ index, float* __restrict__ out) {
  int blk = blockIdx.x;             // 0..511
  int bh = blk >> 4, chunk = blk & 15;
  int h = bh & 7, b = bh >> 3;
  int tid = threadIdx.x;
  int e = tid & 63, sub = tid >> 6;
  int g = chunk * 4 + sub;          // 0..63

  const float* ps = psum + (size_t)bh * 64 * 64;
  float run = 0.f;
  for (int gg = 0; gg < g; ++gg) run += ps[gg * 64 + e];

  int idx[7];
#pragma unroll
  for (int k = 0; k < 7; k++) idx[k] = index[k];

  const float* Vbase = V + (size_t)(b * 2048) * 512 + h * 64 + e;
  float* obase = out + (size_t)bh * 2048 * 64 + e;

  int l0 = g * 32;
#pragma unroll 4
  for (int l = l0; l < l0 + 32; ++l) {
    run += Vbase[(size_t)l * 512];
    float o = run;
    bool special = false;
#pragma unroll
    for (int k = 0; k < 7; k++) special = special || (idx[k] == l);
    if (special) o = run / (float)(l + 1);
    obase[(size_t)l * 64] = o;
  }
}

extern "C" void kernel_launch(void* const* d_in, const int* in_sizes, int n_in,
                              void* d_out, int out_size, void* d_ws, size_t ws_size,
                              hipStream_t stream) {
  const float* Q = (const float*)d_in[0];  // (4,2048,512)
  const float* K = (const float*)d_in[1];
  const float* V = (const float*)d_in[2];
  float* out = (float*)d_out;              // (4,8,2048,64)

  // Workspace layout:
  unsigned short* Z = (unsigned short*)d_ws;        // 4*4096*512 bf16 = 16.8 MB
  float* base = (float*)d_ws + 4 * 4096 * 512 / 2;  // after Z
  float* part = base;                               // 4*4096*64 = 1M floats
  float* lse_t = base + 4 * 4096 * 64;              // 16384
  float* lse_i = lse_t + 16384;                     // 16384
  float* posd = lse_i + 16384;                      // 8192
  int* idx = (int*)(posd + 8192);                   // 8
  float* psum = part;  // 32*64*64 floats = 512 KB, reuses dead `part`

  convert_bf16_kernel<<<4096, 256, 0, stream>>>(Q, K, Z);
  // Blocks 0..2111: gram tiles; 2112..2367: fused instance path.
  temporal_gemm_kernel<<<2368, 256, 0, stream>>>(Z, part, lse_i, posd);
  merge_row_kernel<<<64, 256, 0, stream>>>(part, lse_t);
  // Block 0: combine+top7; blocks 1..512: cumsum psum (part is dead after
  // merge_row; safe to overlay).
  combine_psum_kernel<<<513, 256, 0, stream>>>(lse_i, lse_t, posd, idx, V,
                                               psum);
  cumsum_write_kernel<<<512, 256, 0, stream>>>(V, psum, idx, out);
}